// Round 1
// baseline (745.334 us; speedup 1.0000x reference)
//
#include <hip/hip_runtime.h>

typedef __bf16 bf16x8 __attribute__((ext_vector_type(8)));
typedef float f32x4 __attribute__((ext_vector_type(4)));

#define NROWS 4096   // B*T
#define DM 2048
#define LAT 512
#define NH 16
#define DH 128

__device__ __forceinline__ unsigned short f2bf(float f) {
    union { float f; unsigned u; } v; v.f = f;
    unsigned r = v.u + 0x7fffu + ((v.u >> 16) & 1u);
    return (unsigned short)(r >> 16);
}

// ---------- elementwise f32 -> bf16 (vectorized) ----------
__global__ __launch_bounds__(256) void f32_to_bf16_kernel(const float* __restrict__ x,
                                                          unsigned short* __restrict__ y, int n) {
    int i = (blockIdx.x * 256 + threadIdx.x) * 4;
    if (i >= n) return;
    float4 v = *(const float4*)(x + i);
    y[i + 0] = f2bf(v.x); y[i + 1] = f2bf(v.y);
    y[i + 2] = f2bf(v.z); y[i + 3] = f2bf(v.w);
}

// ---------- weight transpose + convert: W[K][N] f32 -> Wt[N][K] bf16 ----------
__global__ __launch_bounds__(256) void transpose_w_kernel(const float* __restrict__ W,
                                                          unsigned short* __restrict__ Wt,
                                                          int K, int N) {
    __shared__ float tile[32][33];
    int nb = blockIdx.x * 32, kb = blockIdx.y * 32;
    int tx = threadIdx.x, ty = threadIdx.y; // 32 x 8
    #pragma unroll
    for (int i = 0; i < 32; i += 8)
        tile[ty + i][tx] = W[(size_t)(kb + ty + i) * N + nb + tx];
    __syncthreads();
    #pragma unroll
    for (int i = 0; i < 32; i += 8)
        Wt[(size_t)(nb + ty + i) * K + kb + tx] = f2bf(tile[tx][ty + i]);
}

// ---------- RoPE table: cos/sin [T][16] ----------
__global__ __launch_bounds__(256) void rope_table_kernel(float* __restrict__ cs, float* __restrict__ sn) {
    int idx = blockIdx.x * 256 + threadIdx.x; // 2048*16
    int i = idx & 15, t = idx >> 4;
    float inv = powf(10000.0f, -(float)i / 16.0f);
    float a = (float)t * inv;
    cs[idx] = cosf(a);
    sn[idx] = sinf(a);
}

// ---------- RoPE apply: xin [4096][512] f32 -> bf16 cols 96..127 of dst[4096][2048] (+opt f32 out) ----------
__global__ __launch_bounds__(256) void rope_apply_kernel(const float* __restrict__ xin,
                                                         const float* __restrict__ cs,
                                                         const float* __restrict__ sn,
                                                         unsigned short* __restrict__ out_bf,
                                                         float* __restrict__ out_f32) {
    int idx = blockIdx.x * 256 + threadIdx.x; // 4096*16*16
    int i = idx & 15, h = (idx >> 4) & 15, row = idx >> 8;
    int t = row & 2047;
    const float* xr = xin + (size_t)row * 512 + h * 32;
    float x1 = xr[i], x2 = xr[16 + i];
    float c = cs[t * 16 + i], s = sn[t * 16 + i];
    float o1 = x1 * c - x2 * s;
    float o2 = x2 * c + x1 * s;
    unsigned short* ob = out_bf + (size_t)row * 2048 + h * 128 + 96;
    ob[i] = f2bf(o1);
    ob[16 + i] = f2bf(o2);
    if (out_f32) {
        float* of = out_f32 + (size_t)row * 512 + h * 32;
        of[i] = o1; of[16 + i] = o2;
    }
}

// ---------- generic bf16 GEMM: C[M][N] = A[M][K] @ Wt[N][K]^T + bias ----------
// 128x128 tile, 4 waves (2x2 of 64x64), 16x16x32 MFMA. LDS rows padded +8 bf16.
__global__ __launch_bounds__(256) void gemm_bf16_kernel(const unsigned short* __restrict__ A,
                                                        const unsigned short* __restrict__ Bt,
                                                        const float* __restrict__ bias,
                                                        float* __restrict__ Cf,
                                                        unsigned short* __restrict__ Cb,
                                                        int M, int N, int K, int ldcb, int remap) {
    __shared__ __align__(16) unsigned short As[128 * 40];
    __shared__ __align__(16) unsigned short Bs[128 * 40];
    const int tid = threadIdx.x;
    const int mb = blockIdx.x * 128;
    const int nb = blockIdx.y * 128;
    const int w = tid >> 6, lane = tid & 63;
    const int wr = (w >> 1) * 64, wc = (w & 1) * 64;
    const int l15 = lane & 15, l4 = lane >> 4;

    f32x4 acc[4][4] = {};

    for (int k0 = 0; k0 < K; k0 += 32) {
        __syncthreads();
        #pragma unroll
        for (int i = 0; i < 2; ++i) {
            int c = tid + 256 * i;
            int row = c >> 2, ko = (c & 3) << 3;
            *(uint4*)(As + row * 40 + ko) = *(const uint4*)(A + (size_t)(mb + row) * K + k0 + ko);
            *(uint4*)(Bs + row * 40 + ko) = *(const uint4*)(Bt + (size_t)(nb + row) * K + k0 + ko);
        }
        __syncthreads();
        bf16x8 af[4], bfr[4];
        #pragma unroll
        for (int mi = 0; mi < 4; ++mi)
            af[mi] = *(const bf16x8*)(As + (wr + mi * 16 + l15) * 40 + l4 * 8);
        #pragma unroll
        for (int ni = 0; ni < 4; ++ni)
            bfr[ni] = *(const bf16x8*)(Bs + (wc + ni * 16 + l15) * 40 + l4 * 8);
        #pragma unroll
        for (int mi = 0; mi < 4; ++mi)
            #pragma unroll
            for (int ni = 0; ni < 4; ++ni)
                acc[mi][ni] = __builtin_amdgcn_mfma_f32_16x16x32_bf16(af[mi], bfr[ni], acc[mi][ni], 0, 0, 0);
    }

    #pragma unroll
    for (int mi = 0; mi < 4; ++mi) {
        #pragma unroll
        for (int ni = 0; ni < 4; ++ni) {
            int col = nb + wc + ni * 16 + l15;
            float bv = bias ? bias[col] : 0.0f;
            int ocol = remap ? ((col / 96) * 128 + (col % 96)) : col;
            #pragma unroll
            for (int r = 0; r < 4; ++r) {
                int row = mb + wr + mi * 16 + l4 * 4 + r;
                float v = acc[mi][ni][r] + bv;
                if (Cf) Cf[(size_t)row * N + col] = v;
                if (Cb) Cb[(size_t)row * ldcb + ocol] = f2bf(v);
            }
        }
    }
}

// ---------- flash attention, non-causal, bf16 MFMA ----------
// grid: (T/64, B*NH). block: 256 (4 waves). wave w handles 16 q-rows.
__global__ __launch_bounds__(256) void attn_kernel(const unsigned short* __restrict__ Q,
                                                   const unsigned short* __restrict__ Kb,
                                                   const unsigned short* __restrict__ Vb,
                                                   unsigned short* __restrict__ O) {
    __shared__ __align__(16) unsigned short Ks[32 * 136]; // 32 keys x 128 d (+8 pad)
    __shared__ __align__(16) unsigned short Vt[128 * 40]; // 128 d x 32 keys (+8 pad)
    __shared__ __align__(16) unsigned short Ps[64 * 40];  // 64 q x 32 keys (+8 pad)

    const int tid = threadIdx.x, w = tid >> 6, lane = tid & 63;
    const int l15 = lane & 15, l4 = lane >> 4;
    const int bh = blockIdx.y, b = bh >> 4, h = bh & 15;
    const int qt = blockIdx.x * 64 + w * 16;
    const float scale = 0.08838834764831845f; // 1/sqrt(128)

    // Q fragments: rows qt + l15, d = kc*32 + l4*8 .. +7
    bf16x8 qf[4];
    #pragma unroll
    for (int kc = 0; kc < 4; ++kc)
        qf[kc] = *(const bf16x8*)(Q + (size_t)(b * 2048 + qt + l15) * 2048 + h * 128 + kc * 32 + l4 * 8);

    f32x4 acc[8] = {};
    float m_run[4], l_run[4];
    #pragma unroll
    for (int r = 0; r < 4; ++r) { m_run[r] = -1e30f; l_run[r] = 0.0f; }

    for (int kt0 = 0; kt0 < 2048; kt0 += 32) {
        __syncthreads(); // previous tile's LDS reads done
        // stage K tile (row-major) and V tile (transposed)
        #pragma unroll
        for (int i = 0; i < 2; ++i) {
            int c = tid + 256 * i;
            int key = c >> 4, doff = (c & 15) << 3;
            const size_t gsrc = (size_t)(b * 2048 + kt0 + key) * 2048 + h * 128 + doff;
            *(uint4*)(Ks + key * 136 + doff) = *(const uint4*)(Kb + gsrc);
            union { uint4 v; unsigned short u[8]; } tv;
            tv.v = *(const uint4*)(Vb + gsrc);
            #pragma unroll
            for (int j = 0; j < 8; ++j) Vt[(doff + j) * 40 + key] = tv.u[j];
        }
        __syncthreads();

        // scores: S[16 q][32 k] as two 16-col groups
        f32x4 s[2];
        #pragma unroll
        for (int g = 0; g < 2; ++g) {
            f32x4 sg = {0.0f, 0.0f, 0.0f, 0.0f};
            #pragma unroll
            for (int kc = 0; kc < 4; ++kc) {
                bf16x8 kf = *(const bf16x8*)(Ks + (g * 16 + l15) * 136 + kc * 32 + l4 * 8);
                sg = __builtin_amdgcn_mfma_f32_16x16x32_bf16(qf[kc], kf, sg, 0, 0, 0);
            }
            s[g] = sg;
        }

        // online softmax per q-row (row r of this lane group; 16-lane butterfly over key cols)
        float p0[4], p1[4];
        #pragma unroll
        for (int r = 0; r < 4; ++r) {
            float s0 = s[0][r] * scale, s1 = s[1][r] * scale;
            float mt = fmaxf(s0, s1);
            #pragma unroll
            for (int msk = 1; msk < 16; msk <<= 1) mt = fmaxf(mt, __shfl_xor(mt, msk, 64));
            float mnew = fmaxf(m_run[r], mt);
            float f = __expf(m_run[r] - mnew);
            float e0 = __expf(s0 - mnew), e1 = __expf(s1 - mnew);
            float rs = e0 + e1;
            #pragma unroll
            for (int msk = 1; msk < 16; msk <<= 1) rs += __shfl_xor(rs, msk, 64);
            l_run[r] = l_run[r] * f + rs;
            m_run[r] = mnew;
            #pragma unroll
            for (int n = 0; n < 8; ++n) acc[n][r] *= f;
            p0[r] = e0; p1[r] = e1;
        }

        // P -> LDS (bf16), then PV
        #pragma unroll
        for (int r = 0; r < 4; ++r) {
            int q = w * 16 + l4 * 4 + r;
            Ps[q * 40 + l15] = f2bf(p0[r]);
            Ps[q * 40 + 16 + l15] = f2bf(p1[r]);
        }
        __syncthreads();
        bf16x8 pf = *(const bf16x8*)(Ps + (w * 16 + l15) * 40 + l4 * 8);
        #pragma unroll
        for (int n = 0; n < 8; ++n) {
            bf16x8 vf = *(const bf16x8*)(Vt + (n * 16 + l15) * 40 + l4 * 8);
            acc[n] = __builtin_amdgcn_mfma_f32_16x16x32_bf16(pf, vf, acc[n], 0, 0, 0);
        }
    }

    // normalize + store
    #pragma unroll
    for (int n = 0; n < 8; ++n)
        #pragma unroll
        for (int r = 0; r < 4; ++r) {
            int row = b * 2048 + qt + l4 * 4 + r;
            float v = acc[n][r] / l_run[r];
            O[(size_t)row * 2048 + h * 128 + n * 16 + l15] = f2bf(v);
        }
}

extern "C" void kernel_launch(void* const* d_in, const int* in_sizes, int n_in,
                              void* d_out, int out_size, void* d_ws, size_t ws_size,
                              hipStream_t stream) {
    (void)in_sizes; (void)n_in; (void)out_size; (void)ws_size;

    const float* input  = (const float*)d_in[0];
    const float* Wdkv_w = (const float*)d_in[3];
    const float* Wdkv_b = (const float*)d_in[4];
    const float* Wdq_w  = (const float*)d_in[5];
    const float* Wdq_b  = (const float*)d_in[6];
    const float* Wuk_w  = (const float*)d_in[7];
    const float* Wuk_b  = (const float*)d_in[8];
    const float* Wuv_w  = (const float*)d_in[9];
    const float* Wuv_b  = (const float*)d_in[10];
    const float* Wuq_w  = (const float*)d_in[11];
    const float* Wuq_b  = (const float*)d_in[12];
    const float* Wqr_w  = (const float*)d_in[13];
    const float* Wqr_b  = (const float*)d_in[14];
    const float* Wkr_w  = (const float*)d_in[15];
    const float* Wkr_b  = (const float*)d_in[16];
    const float* Wo_w   = (const float*)d_in[17];
    const float* Wo_b   = (const float*)d_in[18];

    float* out_main = (float*)d_out;                       // [4096][2048]
    float* out_ckv  = out_main + (size_t)NROWS * DM;       // [4096][512]
    float* out_krot = out_ckv + (size_t)NROWS * LAT;       // [4096][512]

    char* p = (char*)d_ws;
    auto alloc = [&](size_t bytes) { char* r = p; p += (bytes + 255) & ~(size_t)255; return r; };
    unsigned short* x_bf   = (unsigned short*)alloc((size_t)NROWS * DM * 2);
    unsigned short* wdkv_t = (unsigned short*)alloc((size_t)LAT * DM * 2);
    unsigned short* wdq_t  = (unsigned short*)alloc((size_t)LAT * DM * 2);
    unsigned short* wuk_t  = (unsigned short*)alloc((size_t)1536 * LAT * 2);
    unsigned short* wuv_t  = (unsigned short*)alloc((size_t)2048 * LAT * 2);
    unsigned short* wuq_t  = (unsigned short*)alloc((size_t)1536 * LAT * 2);
    unsigned short* wqr_t  = (unsigned short*)alloc((size_t)512 * LAT * 2);
    unsigned short* wkr_t  = (unsigned short*)alloc((size_t)512 * DM * 2);
    unsigned short* wo_t   = (unsigned short*)alloc((size_t)DM * DM * 2);
    unsigned short* ckv_bf = (unsigned short*)alloc((size_t)NROWS * LAT * 2);
    unsigned short* cq_bf  = (unsigned short*)alloc((size_t)NROWS * LAT * 2);
    float*          qrot_f = (float*)alloc((size_t)NROWS * LAT * 4);
    float*          krot_f = (float*)alloc((size_t)NROWS * LAT * 4);
    unsigned short* q_bf   = (unsigned short*)alloc((size_t)NROWS * DM * 2);
    unsigned short* k_bf   = (unsigned short*)alloc((size_t)NROWS * DM * 2);
    unsigned short* v_bf   = (unsigned short*)alloc((size_t)NROWS * DM * 2);
    unsigned short* ao_bf  = (unsigned short*)alloc((size_t)NROWS * DM * 2);
    float*          cos_t  = (float*)alloc((size_t)2048 * 16 * 4);
    float*          sin_t  = (float*)alloc((size_t)2048 * 16 * 4);

    // input -> bf16
    f32_to_bf16_kernel<<<(NROWS * DM) / (256 * 4), 256, 0, stream>>>(input, x_bf, NROWS * DM);

    // weights -> transposed bf16
    auto tw = [&](const float* W, unsigned short* Wt, int K, int N) {
        transpose_w_kernel<<<dim3(N / 32, K / 32), dim3(32, 8), 0, stream>>>(W, Wt, K, N);
    };
    tw(Wdkv_w, wdkv_t, 2048, 512);
    tw(Wdq_w,  wdq_t,  2048, 512);
    tw(Wuk_w,  wuk_t,  512, 1536);
    tw(Wuv_w,  wuv_t,  512, 2048);
    tw(Wuq_w,  wuq_t,  512, 1536);
    tw(Wqr_w,  wqr_t,  512, 512);
    tw(Wkr_w,  wkr_t,  2048, 512);
    tw(Wo_w,   wo_t,   2048, 2048);

    rope_table_kernel<<<(2048 * 16) / 256, 256, 0, stream>>>(cos_t, sin_t);

    auto gemm = [&](const unsigned short* A, const unsigned short* Bt, const float* bias,
                    float* Cf, unsigned short* Cb, int M, int N, int K, int ldcb, int remap) {
        gemm_bf16_kernel<<<dim3(M / 128, N / 128), 256, 0, stream>>>(A, Bt, bias, Cf, Cb, M, N, K, ldcb, remap);
    };

    // projections
    gemm(x_bf,   wdkv_t, Wdkv_b, out_ckv, ckv_bf, NROWS, 512,  2048, 512,  0); // c_kv (output + bf16)
    gemm(x_bf,   wdq_t,  Wdq_b,  nullptr, cq_bf,  NROWS, 512,  2048, 512,  0); // c_q
    gemm(ckv_bf, wuk_t,  Wuk_b,  nullptr, k_bf,   NROWS, 1536, 512,  2048, 1); // k_base -> k[,0..95]
    gemm(ckv_bf, wuv_t,  Wuv_b,  nullptr, v_bf,   NROWS, 2048, 512,  2048, 0); // v
    gemm(cq_bf,  wuq_t,  Wuq_b,  nullptr, q_bf,   NROWS, 1536, 512,  2048, 1); // q_base -> q[,0..95]
    gemm(cq_bf,  wqr_t,  Wqr_b,  qrot_f,  nullptr, NROWS, 512, 512,  0,    0); // q_rot pre-rope
    gemm(x_bf,   wkr_t,  Wkr_b,  krot_f,  nullptr, NROWS, 512, 2048, 0,    0); // k_rot pre-rope

    // rope: fill q/k cols 96..127; k_rot also to d_out (fp32)
    rope_apply_kernel<<<(NROWS * 16 * 16) / 256, 256, 0, stream>>>(qrot_f, cos_t, sin_t, q_bf, nullptr);
    rope_apply_kernel<<<(NROWS * 16 * 16) / 256, 256, 0, stream>>>(krot_f, cos_t, sin_t, k_bf, out_krot);

    // attention
    attn_kernel<<<dim3(2048 / 64, 2 * NH), 256, 0, stream>>>(q_bf, k_bf, v_bf, ao_bf);

    // output projection
    gemm(ao_bf, wo_t, Wo_b, out_main, nullptr, NROWS, 2048, 2048, 0, 0);
}

// Round 2
// 398.821 us; speedup vs baseline: 1.8688x; 1.8688x over previous
//
#include <hip/hip_runtime.h>

typedef __bf16 bf16x8 __attribute__((ext_vector_type(8)));
typedef float f32x4 __attribute__((ext_vector_type(4)));

#define NROWS 4096   // B*T
#define DM 2048
#define LAT 512
#define NH 16
#define DH 128

__device__ __forceinline__ unsigned short f2bf(float f) {
    union { float f; unsigned u; } v; v.f = f;
    unsigned r = v.u + 0x7fffu + ((v.u >> 16) & 1u);
    return (unsigned short)(r >> 16);
}
__device__ __forceinline__ unsigned short bfc(float x) {
    union { __bf16 b; unsigned short u; } v; v.b = (__bf16)x; return v.u;
}
__device__ __forceinline__ void gload16(const void* g, void* l) {
    __builtin_amdgcn_global_load_lds((const __attribute__((address_space(1))) unsigned int*)g,
                                     (__attribute__((address_space(3))) unsigned int*)l, 16, 0, 0);
}
__device__ __forceinline__ f32x4 vmax4(f32x4 a, f32x4 b) {
    f32x4 r; r[0]=fmaxf(a[0],b[0]); r[1]=fmaxf(a[1],b[1]); r[2]=fmaxf(a[2],b[2]); r[3]=fmaxf(a[3],b[3]); return r;
}

// ---------- elementwise f32 -> bf16 (vectorized) ----------
__global__ __launch_bounds__(256) void f32_to_bf16_kernel(const float* __restrict__ x,
                                                          unsigned short* __restrict__ y, int n) {
    int i = (blockIdx.x * 256 + threadIdx.x) * 4;
    if (i >= n) return;
    float4 v = *(const float4*)(x + i);
    y[i + 0] = f2bf(v.x); y[i + 1] = f2bf(v.y);
    y[i + 2] = f2bf(v.z); y[i + 3] = f2bf(v.w);
}

// ---------- weight transpose + convert: W[K][N] f32 -> Wt[N][K] bf16 ----------
__global__ __launch_bounds__(256) void transpose_w_kernel(const float* __restrict__ W,
                                                          unsigned short* __restrict__ Wt,
                                                          int K, int N) {
    __shared__ float tile[32][33];
    int nb = blockIdx.x * 32, kb = blockIdx.y * 32;
    int tx = threadIdx.x, ty = threadIdx.y; // 32 x 8
    #pragma unroll
    for (int i = 0; i < 32; i += 8)
        tile[ty + i][tx] = W[(size_t)(kb + ty + i) * N + nb + tx];
    __syncthreads();
    #pragma unroll
    for (int i = 0; i < 32; i += 8)
        Wt[(size_t)(nb + ty + i) * K + kb + tx] = f2bf(tile[tx][ty + i]);
}

// ---------- RoPE table: cos/sin [T][16] ----------
__global__ __launch_bounds__(256) void rope_table_kernel(float* __restrict__ cs, float* __restrict__ sn) {
    int idx = blockIdx.x * 256 + threadIdx.x; // 2048*16
    int i = idx & 15, t = idx >> 4;
    float inv = powf(10000.0f, -(float)i / 16.0f);
    float a = (float)t * inv;
    cs[idx] = cosf(a);
    sn[idx] = sinf(a);
}

// ---------- RoPE apply ----------
__global__ __launch_bounds__(256) void rope_apply_kernel(const float* __restrict__ xin,
                                                         const float* __restrict__ cs,
                                                         const float* __restrict__ sn,
                                                         unsigned short* __restrict__ out_bf,
                                                         float* __restrict__ out_f32) {
    int idx = blockIdx.x * 256 + threadIdx.x; // 4096*16*16
    int i = idx & 15, h = (idx >> 4) & 15, row = idx >> 8;
    int t = row & 2047;
    const float* xr = xin + (size_t)row * 512 + h * 32;
    float x1 = xr[i], x2 = xr[16 + i];
    float c = cs[t * 16 + i], s = sn[t * 16 + i];
    float o1 = x1 * c - x2 * s;
    float o2 = x2 * c + x1 * s;
    unsigned short* ob = out_bf + (size_t)row * 2048 + h * 128 + 96;
    ob[i] = f2bf(o1);
    ob[16 + i] = f2bf(o2);
    if (out_f32) {
        float* of = out_f32 + (size_t)row * 512 + h * 32;
        of[i] = o1; of[16 + i] = o2;
    }
}

// ---------- m97-structure bf16 GEMM: C[M][N] = A[M][K] @ Bt[N][K]^T + bias ----------
// BM=128, BN in {64,128}; 4 waves 2x2; linear LDS [row][32]; global_load_lds staging.
// mode: 0 = Cb row-major; 1 = Cb row-major with 96->128 col remap; 2 = Cb transposed [N][ldcb]
template<int BN>
__global__ __launch_bounds__(256) void gemm_bf16_kernel(const unsigned short* __restrict__ A,
                                                        const unsigned short* __restrict__ Bt,
                                                        const float* __restrict__ bias,
                                                        float* __restrict__ Cf,
                                                        unsigned short* __restrict__ Cb,
                                                        int M, int N, int K, int ldcb, int mode) {
    constexpr int NF = BN / 32;           // B-frags per wave
    __shared__ __align__(16) unsigned short As[128 * 32];
    __shared__ __align__(16) unsigned short Bs[BN * 32];
    const int tid = threadIdx.x;
    const int mb = blockIdx.x * 128;
    const int nb = blockIdx.y * BN;
    const int w = tid >> 6, lane = tid & 63;
    const int wr = (w >> 1) * 64, wc = (w & 1) * (BN / 2);
    const int l15 = lane & 15, l4 = lane >> 4;
    const int srow = lane >> 2, sko = (lane & 3) * 8;
    constexpr int NCH = 8 + BN / 16;      // 1KB chunks per k-step

    f32x4 acc[4][NF] = {};

    for (int k0 = 0; k0 < K; k0 += 32) {
        __syncthreads();
        #pragma unroll
        for (int c = 0; c < NCH; c += 4) {
            int cc = c + w;
            if (cc < 8) {
                int row = cc * 16 + srow;
                gload16(A + (size_t)(mb + row) * K + k0 + sko, As + cc * 512);
            } else {
                int row = (cc - 8) * 16 + srow;
                gload16(Bt + (size_t)(nb + row) * K + k0 + sko, Bs + (cc - 8) * 512);
            }
        }
        __syncthreads();
        bf16x8 af[4], bfr[NF];
        #pragma unroll
        for (int mi = 0; mi < 4; ++mi)
            af[mi] = *(const bf16x8*)(As + (wr + mi * 16 + l15) * 32 + l4 * 8);
        #pragma unroll
        for (int ni = 0; ni < NF; ++ni)
            bfr[ni] = *(const bf16x8*)(Bs + (wc + ni * 16 + l15) * 32 + l4 * 8);
        #pragma unroll
        for (int mi = 0; mi < 4; ++mi)
            #pragma unroll
            for (int ni = 0; ni < NF; ++ni)
                acc[mi][ni] = __builtin_amdgcn_mfma_f32_16x16x32_bf16(af[mi], bfr[ni], acc[mi][ni], 0, 0, 0);
    }

    #pragma unroll
    for (int mi = 0; mi < 4; ++mi) {
        #pragma unroll
        for (int ni = 0; ni < NF; ++ni) {
            int col = nb + wc + ni * 16 + l15;
            float bv = bias ? bias[col] : 0.0f;
            float v0 = acc[mi][ni][0] + bv, v1 = acc[mi][ni][1] + bv;
            float v2 = acc[mi][ni][2] + bv, v3 = acc[mi][ni][3] + bv;
            int row0 = mb + wr + mi * 16 + l4 * 4;
            if (Cf) {
                Cf[(size_t)(row0 + 0) * N + col] = v0;
                Cf[(size_t)(row0 + 1) * N + col] = v1;
                Cf[(size_t)(row0 + 2) * N + col] = v2;
                Cf[(size_t)(row0 + 3) * N + col] = v3;
            }
            if (Cb) {
                if (mode == 2) {
                    ushort4 pv;
                    pv.x = f2bf(v0); pv.y = f2bf(v1); pv.z = f2bf(v2); pv.w = f2bf(v3);
                    *(ushort4*)(Cb + (size_t)col * ldcb + row0) = pv;
                } else {
                    int ocol = (mode == 1) ? ((col / 96) * 128 + (col % 96)) : col;
                    Cb[(size_t)(row0 + 0) * ldcb + ocol] = f2bf(v0);
                    Cb[(size_t)(row0 + 1) * ldcb + ocol] = f2bf(v1);
                    Cb[(size_t)(row0 + 2) * ldcb + ocol] = f2bf(v2);
                    Cb[(size_t)(row0 + 3) * ldcb + ocol] = f2bf(v3);
                }
            }
        }
    }
}

// ---------- flash attention, non-causal, bf16 MFMA ----------
// grid (16, 32): 128 q-rows/block (4 waves x 32), KVBLK=64, double-buffered gload_lds staging,
// XOR-swizzled K/V/P LDS tiles, defer-max online softmax. V comes pre-transposed: Vtg[2048][4096].
__global__ __launch_bounds__(256, 2) void attn_kernel(const unsigned short* __restrict__ Q,
                                                      const unsigned short* __restrict__ Kb,
                                                      const unsigned short* __restrict__ Vtg,
                                                      unsigned short* __restrict__ O) {
    __shared__ __align__(16) unsigned short Ks[2][64 * 128];  // [key][d^((key&7)<<3)]
    __shared__ __align__(16) unsigned short Vs[2][128 * 64];  // [d][k^((d&7)<<3)]
    __shared__ __align__(16) unsigned short Ps[4 * 32 * 64];  // per wave [q][k^((q&7)<<3)]

    const int tid = threadIdx.x, w = tid >> 6, lane = tid & 63;
    const int l15 = lane & 15, l4 = lane >> 4;
    const int bh = blockIdx.y, b = bh >> 4, h = bh & 15;
    const int qt = blockIdx.x * 128 + w * 32;
    const float scale = 0.08838834764831845f; // 1/sqrt(128)
    unsigned short* Pw = Ps + w * 2048;

    // Q fragments: qf[m][kc] rows qt+m*16+l15, d = kc*32 + l4*8
    bf16x8 qf[2][4];
    #pragma unroll
    for (int m = 0; m < 2; ++m)
        #pragma unroll
        for (int kc = 0; kc < 4; ++kc)
            qf[m][kc] = *(const bf16x8*)(Q + (size_t)(b * 2048 + qt + m * 16 + l15) * 2048 + h * 128 + kc * 32 + l4 * 8);

    f32x4 acc[2][8] = {};
    f32x4 mrun[2], lrun[2];
    #pragma unroll
    for (int m = 0; m < 2; ++m) {
        mrun[m] = (f32x4){-1e30f, -1e30f, -1e30f, -1e30f};
        lrun[m] = (f32x4){0.0f, 0.0f, 0.0f, 0.0f};
    }

    const int kl15 = lane >> 4, kd0 = lane & 15;   // K staging sub-indices
    const int vr = lane >> 3, vk = lane & 7;       // V staging sub-indices

    // STAGE(buf, kt): wave w stages chunks w*4..w*4+3 of K and V tiles
    auto STAGE = [&](int buf, int kt) {
        #pragma unroll
        for (int i = 0; i < 4; ++i) {
            int c = w * 4 + i;
            int key = c * 4 + kl15;
            int d0 = (kd0 * 8) ^ ((key & 7) << 3);
            gload16(Kb + (size_t)(b * 2048 + kt + key) * 2048 + h * 128 + d0, &Ks[buf][c * 512]);
            int dv = c * 8 + vr;
            int k0 = (vk * 8) ^ ((dv & 7) << 3);
            gload16(Vtg + (size_t)(h * 128 + dv) * 4096 + b * 2048 + kt + k0, &Vs[buf][c * 512]);
        }
    };

    STAGE(0, 0);
    __syncthreads();

    for (int t = 0; t < 32; ++t) {
        const int buf = t & 1;
        if (t < 31) STAGE(buf ^ 1, (t + 1) * 64);

        // QK^T: s[m][g] over 64 keys (4 groups of 16)
        f32x4 s[2][4] = {};
        #pragma unroll
        for (int g = 0; g < 4; ++g)
            #pragma unroll
            for (int kc = 0; kc < 4; ++kc) {
                int key = g * 16 + l15;
                bf16x8 kf = *(const bf16x8*)(&Ks[buf][key * 128 + ((kc * 32 + l4 * 8) ^ ((key & 7) << 3))]);
                #pragma unroll
                for (int m = 0; m < 2; ++m)
                    s[m][g] = __builtin_amdgcn_mfma_f32_16x16x32_bf16(qf[m][kc], kf, s[m][g], 0, 0, 0);
            }
        #pragma unroll
        for (int m = 0; m < 2; ++m)
            #pragma unroll
            for (int g = 0; g < 4; ++g)
                s[m][g] *= scale;

        // row max (per m: component r over 4 g-regs, butterfly over 16 key-lanes)
        f32x4 pm[2];
        #pragma unroll
        for (int m = 0; m < 2; ++m)
            pm[m] = vmax4(vmax4(s[m][0], s[m][1]), vmax4(s[m][2], s[m][3]));
        #pragma unroll
        for (int m = 0; m < 2; ++m)
            #pragma unroll
            for (int r = 0; r < 4; ++r)
                #pragma unroll
                for (int msk = 1; msk < 16; msk <<= 1)
                    pm[m][r] = fmaxf(pm[m][r], __shfl_xor(pm[m][r], msk, 64));

        // defer-max: only rescale when max grows by > 8
        bool up = false;
        #pragma unroll
        for (int m = 0; m < 2; ++m)
            #pragma unroll
            for (int r = 0; r < 4; ++r)
                up = up || (pm[m][r] > mrun[m][r] + 8.0f);
        if (__any(up)) {
            #pragma unroll
            for (int m = 0; m < 2; ++m) {
                f32x4 mn = vmax4(mrun[m], pm[m]);
                f32x4 f;
                #pragma unroll
                for (int r = 0; r < 4; ++r) f[r] = __expf(mrun[m][r] - mn[r]);
                mrun[m] = mn;
                lrun[m] *= f;
                #pragma unroll
                for (int n = 0; n < 8; ++n) acc[m][n] *= f;
            }
        }

        // P = exp(s - mrun): write to swizzled per-wave LDS, accumulate row sums
        f32x4 rs[2] = {};
        #pragma unroll
        for (int m = 0; m < 2; ++m)
            #pragma unroll
            for (int g = 0; g < 4; ++g) {
                f32x4 e;
                #pragma unroll
                for (int r = 0; r < 4; ++r) e[r] = __expf(s[m][g][r] - mrun[m][r]);
                rs[m] += e;
                #pragma unroll
                for (int r = 0; r < 4; ++r) {
                    int q = m * 16 + l4 * 4 + r;
                    Pw[q * 64 + ((g * 16 + l15) ^ ((q & 7) << 3))] = bfc(e[r]);
                }
            }
        #pragma unroll
        for (int m = 0; m < 2; ++m)
            #pragma unroll
            for (int r = 0; r < 4; ++r) {
                #pragma unroll
                for (int msk = 1; msk < 16; msk <<= 1)
                    rs[m][r] += __shfl_xor(rs[m][r], msk, 64);
                lrun[m][r] += rs[m][r];
            }

        // PV: acc[m][n] += P[32q x 64k] @ V[64k x 128d]
        #pragma unroll
        for (int kc2 = 0; kc2 < 2; ++kc2) {
            bf16x8 pf[2];
            #pragma unroll
            for (int m = 0; m < 2; ++m) {
                int q = m * 16 + l15;
                pf[m] = *(const bf16x8*)(Pw + q * 64 + ((kc2 * 32 + l4 * 8) ^ ((q & 7) << 3)));
            }
            #pragma unroll
            for (int n = 0; n < 8; ++n) {
                int d = n * 16 + l15;
                bf16x8 vf = *(const bf16x8*)(&Vs[buf][d * 64 + ((kc2 * 32 + l4 * 8) ^ ((d & 7) << 3))]);
                #pragma unroll
                for (int m = 0; m < 2; ++m)
                    acc[m][n] = __builtin_amdgcn_mfma_f32_16x16x32_bf16(pf[m], vf, acc[m][n], 0, 0, 0);
            }
        }
        __syncthreads();
    }

    // normalize + store
    #pragma unroll
    for (int m = 0; m < 2; ++m) {
        f32x4 inv;
        #pragma unroll
        for (int r = 0; r < 4; ++r) inv[r] = 1.0f / lrun[m][r];
        #pragma unroll
        for (int n = 0; n < 8; ++n)
            #pragma unroll
            for (int r = 0; r < 4; ++r) {
                int row = b * 2048 + qt + m * 16 + l4 * 4 + r;
                O[(size_t)row * 2048 + h * 128 + n * 16 + l15] = bfc(acc[m][n][r] * inv[r]);
            }
    }
}

extern "C" void kernel_launch(void* const* d_in, const int* in_sizes, int n_in,
                              void* d_out, int out_size, void* d_ws, size_t ws_size,
                              hipStream_t stream) {
    (void)in_sizes; (void)n_in; (void)out_size; (void)ws_size;

    const float* input  = (const float*)d_in[0];
    const float* Wdkv_w = (const float*)d_in[3];
    const float* Wdkv_b = (const float*)d_in[4];
    const float* Wdq_w  = (const float*)d_in[5];
    const float* Wdq_b  = (const float*)d_in[6];
    const float* Wuk_w  = (const float*)d_in[7];
    const float* Wuk_b  = (const float*)d_in[8];
    const float* Wuv_w  = (const float*)d_in[9];
    const float* Wuv_b  = (const float*)d_in[10];
    const float* Wuq_w  = (const float*)d_in[11];
    const float* Wuq_b  = (const float*)d_in[12];
    const float* Wqr_w  = (const float*)d_in[13];
    const float* Wqr_b  = (const float*)d_in[14];
    const float* Wkr_w  = (const float*)d_in[15];
    const float* Wkr_b  = (const float*)d_in[16];
    const float* Wo_w   = (const float*)d_in[17];
    const float* Wo_b   = (const float*)d_in[18];

    float* out_main = (float*)d_out;                       // [4096][2048]
    float* out_ckv  = out_main + (size_t)NROWS * DM;       // [4096][512]
    float* out_krot = out_ckv + (size_t)NROWS * LAT;       // [4096][512]

    char* p = (char*)d_ws;
    auto alloc = [&](size_t bytes) { char* r = p; p += (bytes + 255) & ~(size_t)255; return r; };
    unsigned short* x_bf   = (unsigned short*)alloc((size_t)NROWS * DM * 2);
    unsigned short* wdkv_t = (unsigned short*)alloc((size_t)LAT * DM * 2);
    unsigned short* wdq_t  = (unsigned short*)alloc((size_t)LAT * DM * 2);
    unsigned short* wuk_t  = (unsigned short*)alloc((size_t)1536 * LAT * 2);
    unsigned short* wuv_t  = (unsigned short*)alloc((size_t)2048 * LAT * 2);
    unsigned short* wuq_t  = (unsigned short*)alloc((size_t)1536 * LAT * 2);
    unsigned short* wqr_t  = (unsigned short*)alloc((size_t)512 * LAT * 2);
    unsigned short* wkr_t  = (unsigned short*)alloc((size_t)512 * DM * 2);
    unsigned short* wo_t   = (unsigned short*)alloc((size_t)DM * DM * 2);
    unsigned short* ckv_bf = (unsigned short*)alloc((size_t)NROWS * LAT * 2);
    unsigned short* cq_bf  = (unsigned short*)alloc((size_t)NROWS * LAT * 2);
    float*          qrot_f = (float*)alloc((size_t)NROWS * LAT * 4);
    float*          krot_f = (float*)alloc((size_t)NROWS * LAT * 4);
    unsigned short* q_bf   = (unsigned short*)alloc((size_t)NROWS * DM * 2);
    unsigned short* k_bf   = (unsigned short*)alloc((size_t)NROWS * DM * 2);
    unsigned short* vt_g   = (unsigned short*)alloc((size_t)DM * NROWS * 2);  // V^T [2048][4096]
    unsigned short* ao_bf  = (unsigned short*)alloc((size_t)NROWS * DM * 2);
    float*          cos_t  = (float*)alloc((size_t)2048 * 16 * 4);
    float*          sin_t  = (float*)alloc((size_t)2048 * 16 * 4);

    // input -> bf16
    f32_to_bf16_kernel<<<(NROWS * DM) / (256 * 4), 256, 0, stream>>>(input, x_bf, NROWS * DM);

    // weights -> transposed bf16
    auto tw = [&](const float* W, unsigned short* Wt, int K, int N) {
        transpose_w_kernel<<<dim3(N / 32, K / 32), dim3(32, 8), 0, stream>>>(W, Wt, K, N);
    };
    tw(Wdkv_w, wdkv_t, 2048, 512);
    tw(Wdq_w,  wdq_t,  2048, 512);
    tw(Wuk_w,  wuk_t,  512, 1536);
    tw(Wuv_w,  wuv_t,  512, 2048);
    tw(Wuq_w,  wuq_t,  512, 1536);
    tw(Wqr_w,  wqr_t,  512, 512);
    tw(Wkr_w,  wkr_t,  2048, 512);
    tw(Wo_w,   wo_t,   2048, 2048);

    rope_table_kernel<<<(2048 * 16) / 256, 256, 0, stream>>>(cos_t, sin_t);

    auto gemm128 = [&](const unsigned short* A, const unsigned short* Bt, const float* bias,
                       float* Cf, unsigned short* Cb, int M, int N, int K, int ldcb, int mode) {
        gemm_bf16_kernel<128><<<dim3(M / 128, N / 128), 256, 0, stream>>>(A, Bt, bias, Cf, Cb, M, N, K, ldcb, mode);
    };
    auto gemm64 = [&](const unsigned short* A, const unsigned short* Bt, const float* bias,
                      float* Cf, unsigned short* Cb, int M, int N, int K, int ldcb, int mode) {
        gemm_bf16_kernel<64><<<dim3(M / 128, N / 64), 256, 0, stream>>>(A, Bt, bias, Cf, Cb, M, N, K, ldcb, mode);
    };

    // projections
    gemm64 (x_bf,   wdkv_t, Wdkv_b, out_ckv, ckv_bf, NROWS, 512,  2048, 512,  0); // c_kv (f32 out + bf16)
    gemm64 (x_bf,   wdq_t,  Wdq_b,  nullptr, cq_bf,  NROWS, 512,  2048, 512,  0); // c_q
    gemm128(ckv_bf, wuk_t,  Wuk_b,  nullptr, k_bf,   NROWS, 1536, 512,  2048, 1); // k_base -> k[,0..95]
    gemm128(ckv_bf, wuv_t,  Wuv_b,  nullptr, vt_g,   NROWS, 2048, 512,  4096, 2); // v -> V^T
    gemm128(cq_bf,  wuq_t,  Wuq_b,  nullptr, q_bf,   NROWS, 1536, 512,  2048, 1); // q_base -> q[,0..95]
    gemm64 (cq_bf,  wqr_t,  Wqr_b,  qrot_f,  nullptr, NROWS, 512, 512,  0,    0); // q_rot pre-rope
    gemm64 (x_bf,   wkr_t,  Wkr_b,  krot_f,  nullptr, NROWS, 512, 2048, 0,    0); // k_rot pre-rope

    // rope: fill q/k cols 96..127; k_rot also to d_out (fp32)
    rope_apply_kernel<<<(NROWS * 16 * 16) / 256, 256, 0, stream>>>(qrot_f, cos_t, sin_t, q_bf, nullptr);
    rope_apply_kernel<<<(NROWS * 16 * 16) / 256, 256, 0, stream>>>(krot_f, cos_t, sin_t, k_bf, out_krot);

    // attention
    attn_kernel<<<dim3(16, 2 * NH), 256, 0, stream>>>(q_bf, k_bf, vt_g, ao_bf);

    // output projection
    gemm128(ao_bf, wo_t, Wo_b, out_main, nullptr, NROWS, 2048, 2048, 0, 0);
}

// Round 3
// 359.273 us; speedup vs baseline: 2.0746x; 1.1101x over previous
//
#include <hip/hip_runtime.h>

typedef __bf16 bf16x8 __attribute__((ext_vector_type(8)));
typedef float f32x4 __attribute__((ext_vector_type(4)));
typedef float f32x16 __attribute__((ext_vector_type(16)));

#define NROWS 4096   // B*T
#define DM 2048
#define LAT 512
#define NH 16
#define DH 128

__device__ __forceinline__ unsigned short f2bf(float f) {
    union { float f; unsigned u; } v; v.f = f;
    unsigned r = v.u + 0x7fffu + ((v.u >> 16) & 1u);
    return (unsigned short)(r >> 16);
}
__device__ __forceinline__ void gload16(const void* g, void* l) {
    __builtin_amdgcn_global_load_lds((const __attribute__((address_space(1))) unsigned int*)g,
                                     (__attribute__((address_space(3))) unsigned int*)l, 16, 0, 0);
}
__device__ __forceinline__ unsigned cvtpk_bf16(float lo, float hi) {
    unsigned r;
    asm("v_cvt_pk_bf16_f32 %0, %1, %2" : "=v"(r) : "v"(lo), "v"(hi));
    return r;
}
__device__ __forceinline__ void pl32swap(unsigned& a, unsigned& b) {
    asm("v_permlane32_swap_b32 %0, %1" : "+v"(a), "+v"(b));
}

// ---------- elementwise f32 -> bf16 (vectorized) ----------
__global__ __launch_bounds__(256) void f32_to_bf16_kernel(const float* __restrict__ x,
                                                          unsigned short* __restrict__ y, int n) {
    int i = (blockIdx.x * 256 + threadIdx.x) * 4;
    if (i >= n) return;
    float4 v = *(const float4*)(x + i);
    y[i + 0] = f2bf(v.x); y[i + 1] = f2bf(v.y);
    y[i + 2] = f2bf(v.z); y[i + 3] = f2bf(v.w);
}

// ---------- weight transpose + convert: W[K][N] f32 -> Wt[N][K] bf16 ----------
__global__ __launch_bounds__(256) void transpose_w_kernel(const float* __restrict__ W,
                                                          unsigned short* __restrict__ Wt,
                                                          int K, int N) {
    __shared__ float tile[32][33];
    int nb = blockIdx.x * 32, kb = blockIdx.y * 32;
    int tx = threadIdx.x, ty = threadIdx.y; // 32 x 8
    #pragma unroll
    for (int i = 0; i < 32; i += 8)
        tile[ty + i][tx] = W[(size_t)(kb + ty + i) * N + nb + tx];
    __syncthreads();
    #pragma unroll
    for (int i = 0; i < 32; i += 8)
        Wt[(size_t)(nb + ty + i) * K + kb + tx] = f2bf(tile[tx][ty + i]);
}

// ---------- RoPE table: cos/sin [T][16] ----------
__global__ __launch_bounds__(256) void rope_table_kernel(float* __restrict__ cs, float* __restrict__ sn) {
    int idx = blockIdx.x * 256 + threadIdx.x; // 2048*16
    int i = idx & 15, t = idx >> 4;
    float inv = powf(10000.0f, -(float)i / 16.0f);
    float a = (float)t * inv;
    cs[idx] = cosf(a);
    sn[idx] = sinf(a);
}

// ---------- RoPE apply ----------
__global__ __launch_bounds__(256) void rope_apply_kernel(const float* __restrict__ xin,
                                                         const float* __restrict__ cs,
                                                         const float* __restrict__ sn,
                                                         unsigned short* __restrict__ out_bf,
                                                         float* __restrict__ out_f32) {
    int idx = blockIdx.x * 256 + threadIdx.x; // 4096*16*16
    int i = idx & 15, h = (idx >> 4) & 15, row = idx >> 8;
    int t = row & 2047;
    const float* xr = xin + (size_t)row * 512 + h * 32;
    float x1 = xr[i], x2 = xr[16 + i];
    float c = cs[t * 16 + i], s = sn[t * 16 + i];
    float o1 = x1 * c - x2 * s;
    float o2 = x2 * c + x1 * s;
    unsigned short* ob = out_bf + (size_t)row * 2048 + h * 128 + 96;
    ob[i] = f2bf(o1);
    ob[16 + i] = f2bf(o2);
    if (out_f32) {
        float* of = out_f32 + (size_t)row * 512 + h * 32;
        of[i] = o1; of[16 + i] = o2;
    }
}

// ---------- m97-structure bf16 GEMM: C[M][N] = A[M][K] @ Bt[N][K]^T + bias ----------
template<int BN>
__global__ __launch_bounds__(256) void gemm_bf16_kernel(const unsigned short* __restrict__ A,
                                                        const unsigned short* __restrict__ Bt,
                                                        const float* __restrict__ bias,
                                                        float* __restrict__ Cf,
                                                        unsigned short* __restrict__ Cb,
                                                        int M, int N, int K, int ldcb, int mode) {
    constexpr int NF = BN / 32;           // B-frags per wave
    __shared__ __align__(16) unsigned short As[128 * 32];
    __shared__ __align__(16) unsigned short Bs[BN * 32];
    const int tid = threadIdx.x;
    const int mb = blockIdx.x * 128;
    const int nb = blockIdx.y * BN;
    const int w = tid >> 6, lane = tid & 63;
    const int wr = (w >> 1) * 64, wc = (w & 1) * (BN / 2);
    const int l15 = lane & 15, l4 = lane >> 4;
    const int srow = lane >> 2, sko = (lane & 3) * 8;
    constexpr int NCH = 8 + BN / 16;      // 1KB chunks per k-step

    f32x4 acc[4][NF] = {};

    for (int k0 = 0; k0 < K; k0 += 32) {
        __syncthreads();
        #pragma unroll
        for (int c = 0; c < NCH; c += 4) {
            int cc = c + w;
            if (cc < 8) {
                int row = cc * 16 + srow;
                gload16(A + (size_t)(mb + row) * K + k0 + sko, As + cc * 512);
            } else {
                int row = (cc - 8) * 16 + srow;
                gload16(Bt + (size_t)(nb + row) * K + k0 + sko, Bs + (cc - 8) * 512);
            }
        }
        __syncthreads();
        bf16x8 af[4], bfr[NF];
        #pragma unroll
        for (int mi = 0; mi < 4; ++mi)
            af[mi] = *(const bf16x8*)(As + (wr + mi * 16 + l15) * 32 + l4 * 8);
        #pragma unroll
        for (int ni = 0; ni < NF; ++ni)
            bfr[ni] = *(const bf16x8*)(Bs + (wc + ni * 16 + l15) * 32 + l4 * 8);
        #pragma unroll
        for (int mi = 0; mi < 4; ++mi)
            #pragma unroll
            for (int ni = 0; ni < NF; ++ni)
                acc[mi][ni] = __builtin_amdgcn_mfma_f32_16x16x32_bf16(af[mi], bfr[ni], acc[mi][ni], 0, 0, 0);
    }

    #pragma unroll
    for (int mi = 0; mi < 4; ++mi) {
        #pragma unroll
        for (int ni = 0; ni < NF; ++ni) {
            int col = nb + wc + ni * 16 + l15;
            float bv = bias ? bias[col] : 0.0f;
            float v0 = acc[mi][ni][0] + bv, v1 = acc[mi][ni][1] + bv;
            float v2 = acc[mi][ni][2] + bv, v3 = acc[mi][ni][3] + bv;
            int row0 = mb + wr + mi * 16 + l4 * 4;
            if (Cf) {
                Cf[(size_t)(row0 + 0) * N + col] = v0;
                Cf[(size_t)(row0 + 1) * N + col] = v1;
                Cf[(size_t)(row0 + 2) * N + col] = v2;
                Cf[(size_t)(row0 + 3) * N + col] = v3;
            }
            if (Cb) {
                if (mode == 2) {
                    ushort4 pv;
                    pv.x = f2bf(v0); pv.y = f2bf(v1); pv.z = f2bf(v2); pv.w = f2bf(v3);
                    *(ushort4*)(Cb + (size_t)col * ldcb + row0) = pv;
                } else {
                    int ocol = (mode == 1) ? ((col / 96) * 128 + (col % 96)) : col;
                    Cb[(size_t)(row0 + 0) * ldcb + ocol] = f2bf(v0);
                    Cb[(size_t)(row0 + 1) * ldcb + ocol] = f2bf(v1);
                    Cb[(size_t)(row0 + 2) * ldcb + ocol] = f2bf(v2);
                    Cb[(size_t)(row0 + 3) * ldcb + ocol] = f2bf(v3);
                }
            }
        }
    }
}

// ---------- flash attention: swapped-QK^T 32x32 MFMA, in-register softmax ----------
// grid (16, 32), 4 waves x 32 q-rows. KVBLK=64, dbuf gload_lds staging, XOR-swizzled K/V^T.
// S^T = mfma(K, Q^T): lane col = q -> P row lane-local. O^T = mfma(V^T, P^T): col = q ->
// rescale/normalize are per-lane scalars. P^T B-frag built via cvt_pk_bf16 + permlane32_swap.
__global__ __launch_bounds__(256, 2) void attn_kernel(const unsigned short* __restrict__ Q,
                                                      const unsigned short* __restrict__ Kb,
                                                      const unsigned short* __restrict__ Vtg,
                                                      unsigned short* __restrict__ O) {
    __shared__ __align__(16) unsigned short Ks[2][64 * 128];  // [key][d ^ ((key&7)<<3)]
    __shared__ __align__(16) unsigned short Vs[2][128 * 64];  // [d][k ^ ((d&7)<<3)]

    const int tid = threadIdx.x, w = tid >> 6, lane = tid & 63;
    const int l31 = lane & 31, hi = lane >> 5;
    const int bh = blockIdx.y, b = bh >> 4, h = bh & 15;
    const int qrow = blockIdx.x * 128 + w * 32 + l31;
    const float scale = 0.08838834764831845f;  // 1/sqrt(128)

    // Q B-fragments: qf[s] = Q[qrow][s*16 + hi*8 .. +7]
    bf16x8 qf[8];
    const unsigned short* qptr = Q + (size_t)(b * 2048 + qrow) * 2048 + h * 128 + hi * 8;
    #pragma unroll
    for (int s = 0; s < 8; ++s) qf[s] = *(const bf16x8*)(qptr + s * 16);

    f32x16 acc[4] = {};   // O^T frag: col=q (lane), row d = dg*32 + (reg&3)+8*(reg>>2)+4*hi
    float m_run = -1e30f, l_run = 0.0f;

    const int kl15 = lane >> 4, kd0 = lane & 15;   // K staging sub-indices
    const int vr = lane >> 3, vk = lane & 7;       // V staging sub-indices

    auto STAGE = [&](int buf, int kt) {
        #pragma unroll
        for (int i = 0; i < 4; ++i) {
            int c = w * 4 + i;
            int key = c * 4 + kl15;
            int d0 = (kd0 * 8) ^ ((key & 7) << 3);
            gload16(Kb + (size_t)(b * 2048 + kt + key) * 2048 + h * 128 + d0, &Ks[buf][c * 512]);
            int dv = c * 8 + vr;
            int k0 = (vk * 8) ^ ((dv & 7) << 3);
            gload16(Vtg + (size_t)(h * 128 + dv) * 4096 + b * 2048 + kt + k0, &Vs[buf][c * 512]);
        }
    };

    STAGE(0, 0);
    __syncthreads();

    for (int t = 0; t < 32; ++t) {
        const int buf = t & 1;
        if (t < 31) STAGE(buf ^ 1, (t + 1) * 64);

        #pragma unroll
        for (int g = 0; g < 2; ++g) {
            // ---- QK^T: S^T[key][q], 8 mfma over d=128 ----
            const int key = g * 32 + l31;
            const unsigned short* kbase = &Ks[buf][key * 128];
            const int ksw = (key & 7) << 3;
            f32x16 sc = {};
            __builtin_amdgcn_s_setprio(1);
            #pragma unroll
            for (int s = 0; s < 8; ++s) {
                bf16x8 kf = *(const bf16x8*)(kbase + ((s * 16 + hi * 8) ^ ksw));
                sc = __builtin_amdgcn_mfma_f32_32x32x16_bf16(kf, qf[s], sc, 0, 0, 0);
            }
            __builtin_amdgcn_s_setprio(0);

            // ---- row max (in-register + one cross-half exchange) ----
            float pm = sc[0];
            #pragma unroll
            for (int i = 1; i < 16; ++i) pm = fmaxf(pm, sc[i]);
            pm = fmaxf(pm, __shfl_xor(pm, 32, 64));

            // ---- defer-max: rescale only when raw max grows > 8/scale ----
            if (__any(pm > m_run + 90.51f)) {
                float mn = fmaxf(m_run, pm);
                float f = __expf((m_run - mn) * scale);
                m_run = mn;
                l_run *= f;
                #pragma unroll
                for (int dg = 0; dg < 4; ++dg)
                    #pragma unroll
                    for (int i = 0; i < 16; ++i) acc[dg][i] *= f;
            }
            const float mexp = m_run * scale;

            // ---- P = exp, build P^T frags in-register, PV ----
            float rs = 0.0f;
            #pragma unroll
            for (int s2 = 0; s2 < 2; ++s2) {
                float e[8];
                #pragma unroll
                for (int j = 0; j < 8; ++j) {
                    e[j] = __expf(fmaf(sc[s2 * 8 + j], scale, -mexp));
                    rs += e[j];
                }
                unsigned X0 = cvtpk_bf16(e[0], e[1]), X1 = cvtpk_bf16(e[2], e[3]);
                unsigned Y0 = cvtpk_bf16(e[4], e[5]), Y1 = cvtpk_bf16(e[6], e[7]);
                pl32swap(X0, Y0);
                pl32swap(X1, Y1);
                union { unsigned u[4]; bf16x8 v; } pf;
                pf.u[0] = X0; pf.u[1] = X1; pf.u[2] = Y0; pf.u[3] = Y1;

                const int kofs = g * 32 + s2 * 16 + hi * 8;  // element offset within V^T row
                __builtin_amdgcn_s_setprio(1);
                #pragma unroll
                for (int dg = 0; dg < 4; ++dg) {
                    const int d = dg * 32 + l31;
                    bf16x8 vf = *(const bf16x8*)(&Vs[buf][d * 64 + (kofs ^ ((d & 7) << 3))]);
                    acc[dg] = __builtin_amdgcn_mfma_f32_32x32x16_bf16(vf, pf.v, acc[dg], 0, 0, 0);
                }
                __builtin_amdgcn_s_setprio(0);
            }
            rs += __shfl_xor(rs, 32, 64);
            l_run += rs;
        }
        __syncthreads();
    }

    // ---- normalize + store: lane q holds O[qrow][*]; regs 4k..4k+3 = d consecutive ----
    const float inv = 1.0f / l_run;
    unsigned short* obase = O + (size_t)(b * 2048 + qrow) * 2048 + h * 128;
    #pragma unroll
    for (int dg = 0; dg < 4; ++dg)
        #pragma unroll
        for (int k = 0; k < 4; ++k) {
            ushort4 pv;
            pv.x = f2bf(acc[dg][4 * k + 0] * inv);
            pv.y = f2bf(acc[dg][4 * k + 1] * inv);
            pv.z = f2bf(acc[dg][4 * k + 2] * inv);
            pv.w = f2bf(acc[dg][4 * k + 3] * inv);
            *(ushort4*)(obase + dg * 32 + k * 8 + hi * 4) = pv;
        }
}

extern "C" void kernel_launch(void* const* d_in, const int* in_sizes, int n_in,
                              void* d_out, int out_size, void* d_ws, size_t ws_size,
                              hipStream_t stream) {
    (void)in_sizes; (void)n_in; (void)out_size; (void)ws_size;

    const float* input  = (const float*)d_in[0];
    const float* Wdkv_w = (const float*)d_in[3];
    const float* Wdkv_b = (const float*)d_in[4];
    const float* Wdq_w  = (const float*)d_in[5];
    const float* Wdq_b  = (const float*)d_in[6];
    const float* Wuk_w  = (const float*)d_in[7];
    const float* Wuk_b  = (const float*)d_in[8];
    const float* Wuv_w  = (const float*)d_in[9];
    const float* Wuv_b  = (const float*)d_in[10];
    const float* Wuq_w  = (const float*)d_in[11];
    const float* Wuq_b  = (const float*)d_in[12];
    const float* Wqr_w  = (const float*)d_in[13];
    const float* Wqr_b  = (const float*)d_in[14];
    const float* Wkr_w  = (const float*)d_in[15];
    const float* Wkr_b  = (const float*)d_in[16];
    const float* Wo_w   = (const float*)d_in[17];
    const float* Wo_b   = (const float*)d_in[18];

    float* out_main = (float*)d_out;                       // [4096][2048]
    float* out_ckv  = out_main + (size_t)NROWS * DM;       // [4096][512]
    float* out_krot = out_ckv + (size_t)NROWS * LAT;       // [4096][512]

    char* p = (char*)d_ws;
    auto alloc = [&](size_t bytes) { char* r = p; p += (bytes + 255) & ~(size_t)255; return r; };
    unsigned short* x_bf   = (unsigned short*)alloc((size_t)NROWS * DM * 2);
    unsigned short* wdkv_t = (unsigned short*)alloc((size_t)LAT * DM * 2);
    unsigned short* wdq_t  = (unsigned short*)alloc((size_t)LAT * DM * 2);
    unsigned short* wuk_t  = (unsigned short*)alloc((size_t)1536 * LAT * 2);
    unsigned short* wuv_t  = (unsigned short*)alloc((size_t)2048 * LAT * 2);
    unsigned short* wuq_t  = (unsigned short*)alloc((size_t)1536 * LAT * 2);
    unsigned short* wqr_t  = (unsigned short*)alloc((size_t)512 * LAT * 2);
    unsigned short* wkr_t  = (unsigned short*)alloc((size_t)512 * DM * 2);
    unsigned short* wo_t   = (unsigned short*)alloc((size_t)DM * DM * 2);
    unsigned short* ckv_bf = (unsigned short*)alloc((size_t)NROWS * LAT * 2);
    unsigned short* cq_bf  = (unsigned short*)alloc((size_t)NROWS * LAT * 2);
    float*          qrot_f = (float*)alloc((size_t)NROWS * LAT * 4);
    float*          krot_f = (float*)alloc((size_t)NROWS * LAT * 4);
    unsigned short* q_bf   = (unsigned short*)alloc((size_t)NROWS * DM * 2);
    unsigned short* k_bf   = (unsigned short*)alloc((size_t)NROWS * DM * 2);
    unsigned short* vt_g   = (unsigned short*)alloc((size_t)DM * NROWS * 2);  // V^T [2048][4096]
    unsigned short* ao_bf  = (unsigned short*)alloc((size_t)NROWS * DM * 2);
    float*          cos_t  = (float*)alloc((size_t)2048 * 16 * 4);
    float*          sin_t  = (float*)alloc((size_t)2048 * 16 * 4);

    // input -> bf16
    f32_to_bf16_kernel<<<(NROWS * DM) / (256 * 4), 256, 0, stream>>>(input, x_bf, NROWS * DM);

    // weights -> transposed bf16
    auto tw = [&](const float* W, unsigned short* Wt, int K, int N) {
        transpose_w_kernel<<<dim3(N / 32, K / 32), dim3(32, 8), 0, stream>>>(W, Wt, K, N);
    };
    tw(Wdkv_w, wdkv_t, 2048, 512);
    tw(Wdq_w,  wdq_t,  2048, 512);
    tw(Wuk_w,  wuk_t,  512, 1536);
    tw(Wuv_w,  wuv_t,  512, 2048);
    tw(Wuq_w,  wuq_t,  512, 1536);
    tw(Wqr_w,  wqr_t,  512, 512);
    tw(Wkr_w,  wkr_t,  2048, 512);
    tw(Wo_w,   wo_t,   2048, 2048);

    rope_table_kernel<<<(2048 * 16) / 256, 256, 0, stream>>>(cos_t, sin_t);

    auto gemm128 = [&](const unsigned short* A, const unsigned short* Bt, const float* bias,
                       float* Cf, unsigned short* Cb, int M, int N, int K, int ldcb, int mode) {
        gemm_bf16_kernel<128><<<dim3(M / 128, N / 128), 256, 0, stream>>>(A, Bt, bias, Cf, Cb, M, N, K, ldcb, mode);
    };
    auto gemm64 = [&](const unsigned short* A, const unsigned short* Bt, const float* bias,
                      float* Cf, unsigned short* Cb, int M, int N, int K, int ldcb, int mode) {
        gemm_bf16_kernel<64><<<dim3(M / 128, N / 64), 256, 0, stream>>>(A, Bt, bias, Cf, Cb, M, N, K, ldcb, mode);
    };

    // projections
    gemm64 (x_bf,   wdkv_t, Wdkv_b, out_ckv, ckv_bf, NROWS, 512,  2048, 512,  0); // c_kv
    gemm64 (x_bf,   wdq_t,  Wdq_b,  nullptr, cq_bf,  NROWS, 512,  2048, 512,  0); // c_q
    gemm128(ckv_bf, wuk_t,  Wuk_b,  nullptr, k_bf,   NROWS, 1536, 512,  2048, 1); // k_base -> k[,0..95]
    gemm128(ckv_bf, wuv_t,  Wuv_b,  nullptr, vt_g,   NROWS, 2048, 512,  4096, 2); // v -> V^T
    gemm128(cq_bf,  wuq_t,  Wuq_b,  nullptr, q_bf,   NROWS, 1536, 512,  2048, 1); // q_base -> q[,0..95]
    gemm64 (cq_bf,  wqr_t,  Wqr_b,  qrot_f,  nullptr, NROWS, 512, 512,  0,    0); // q_rot pre-rope
    gemm64 (x_bf,   wkr_t,  Wkr_b,  krot_f,  nullptr, NROWS, 512, 2048, 0,    0); // k_rot pre-rope

    // rope: fill q/k cols 96..127; k_rot also to d_out (fp32)
    rope_apply_kernel<<<(NROWS * 16 * 16) / 256, 256, 0, stream>>>(qrot_f, cos_t, sin_t, q_bf, nullptr);
    rope_apply_kernel<<<(NROWS * 16 * 16) / 256, 256, 0, stream>>>(krot_f, cos_t, sin_t, k_bf, out_krot);

    // attention
    attn_kernel<<<dim3(16, 2 * NH), 256, 0, stream>>>(q_bf, k_bf, vt_g, ao_bf);

    // output projection
    gemm128(ao_bf, wo_t, Wo_b, out_main, nullptr, NROWS, 2048, 2048, 0, 0);
}

// Round 4
// 301.418 us; speedup vs baseline: 2.4728x; 1.1919x over previous
//
#include <hip/hip_runtime.h>

typedef __bf16 bf16x8 __attribute__((ext_vector_type(8)));
typedef float f32x4 __attribute__((ext_vector_type(4)));
typedef float f32x16 __attribute__((ext_vector_type(16)));

#define NROWS 4096   // B*T
#define DM 2048
#define LAT 512
#define NH 16
#define DH 128

__device__ __forceinline__ unsigned short f2bf(float f) {
    union { float f; unsigned u; } v; v.f = f;
    unsigned r = v.u + 0x7fffu + ((v.u >> 16) & 1u);
    return (unsigned short)(r >> 16);
}
__device__ __forceinline__ void gload16(const void* g, void* l) {
    __builtin_amdgcn_global_load_lds((const __attribute__((address_space(1))) unsigned int*)g,
                                     (__attribute__((address_space(3))) unsigned int*)l, 16, 0, 0);
}
__device__ __forceinline__ unsigned cvtpk_bf16(float lo, float hi) {
    unsigned r;
    asm("v_cvt_pk_bf16_f32 %0, %1, %2" : "=v"(r) : "v"(lo), "v"(hi));
    return r;
}
__device__ __forceinline__ void pl32swap(unsigned& a, unsigned& b) {
    asm("v_permlane32_swap_b32 %0, %1" : "+v"(a), "+v"(b));
}

// ---------- elementwise f32 -> bf16 (vectorized) ----------
__global__ __launch_bounds__(256) void f32_to_bf16_kernel(const float* __restrict__ x,
                                                          unsigned short* __restrict__ y, int n) {
    int i = (blockIdx.x * 256 + threadIdx.x) * 4;
    if (i >= n) return;
    float4 v = *(const float4*)(x + i);
    y[i + 0] = f2bf(v.x); y[i + 1] = f2bf(v.y);
    y[i + 2] = f2bf(v.z); y[i + 3] = f2bf(v.w);
}

// ---------- weight transpose + convert: W[K][N] f32 -> Wt[N][K] bf16 ----------
__global__ __launch_bounds__(256) void transpose_w_kernel(const float* __restrict__ W,
                                                          unsigned short* __restrict__ Wt,
                                                          int K, int N) {
    __shared__ float tile[32][33];
    int nb = blockIdx.x * 32, kb = blockIdx.y * 32;
    int tx = threadIdx.x, ty = threadIdx.y; // 32 x 8
    #pragma unroll
    for (int i = 0; i < 32; i += 8)
        tile[ty + i][tx] = W[(size_t)(kb + ty + i) * N + nb + tx];
    __syncthreads();
    #pragma unroll
    for (int i = 0; i < 32; i += 8)
        Wt[(size_t)(nb + ty + i) * K + kb + tx] = f2bf(tile[tx][ty + i]);
}

// ---------- RoPE table: cos/sin [T][16] ----------
__global__ __launch_bounds__(256) void rope_table_kernel(float* __restrict__ cs, float* __restrict__ sn) {
    int idx = blockIdx.x * 256 + threadIdx.x; // 2048*16
    int i = idx & 15, t = idx >> 4;
    float inv = powf(10000.0f, -(float)i / 16.0f);
    float a = (float)t * inv;
    cs[idx] = cosf(a);
    sn[idx] = sinf(a);
}

// ---------- fused bf16 GEMM: C[M][Nfused] = A[M][K] @ Bt[Nfused][K]^T + biascat ----------
// m97 structure: 128x128 tile, 4 waves 2x2, linear LDS [row][32], gload_lds staging.
// Epilogue routed per blockIdx.y range (all range boundaries are multiples of 128):
//  which=0 (G1, N=1536): by<4 -> c_kv (f32 outF + bf16 outB0); by<8 -> c_q (outB1);
//                        else -> k_rot: RoPE -> outRope (f32) + k heads cols 96..127 (outB0k)
//  which=1 (G2, N=3584): by<12 -> k_base 96->128 remap (outB0); else -> V^T (outB1, [d][4096])
//  which=2 (G3, N=2048): by<12 -> q_base remap (outB0); else -> q_rot: RoPE -> q cols 96..127
//  which=3 (G4, N=2048): outF = final output (f32)
__global__ __launch_bounds__(256) void gemm_fused_kernel(const unsigned short* __restrict__ A,
                                                         const unsigned short* __restrict__ Bt,
                                                         const float* __restrict__ biascat,
                                                         int K, int which,
                                                         float* __restrict__ outF,
                                                         unsigned short* __restrict__ outB0,
                                                         unsigned short* __restrict__ outB1,
                                                         unsigned short* __restrict__ outB0k,
                                                         float* __restrict__ outRope,
                                                         const float* __restrict__ cs,
                                                         const float* __restrict__ sn) {
    __shared__ __align__(16) unsigned short As[128 * 32];
    __shared__ __align__(16) unsigned short Bs[128 * 32];
    const int tid = threadIdx.x;
    const int mb = blockIdx.x * 128;
    const int by = blockIdx.y, nb = by * 128;
    const int w = tid >> 6, lane = tid & 63;
    const int wr = (w >> 1) * 64, wc = (w & 1) * 64;
    const int l15 = lane & 15, l4 = lane >> 4;
    const int srow = lane >> 2, sko = (lane & 3) * 8;

    f32x4 acc[4][4] = {};

    for (int k0 = 0; k0 < K; k0 += 32) {
        __syncthreads();
        #pragma unroll
        for (int c = 0; c < 16; c += 4) {
            int cc = c + w;
            if (cc < 8)
                gload16(A + (size_t)(mb + cc * 16 + srow) * K + k0 + sko, As + cc * 512);
            else
                gload16(Bt + (size_t)(nb + (cc - 8) * 16 + srow) * K + k0 + sko, Bs + (cc - 8) * 512);
        }
        __syncthreads();
        bf16x8 af[4], bfr[4];
        #pragma unroll
        for (int mi = 0; mi < 4; ++mi)
            af[mi] = *(const bf16x8*)(As + (wr + mi * 16 + l15) * 32 + l4 * 8);
        #pragma unroll
        for (int ni = 0; ni < 4; ++ni)
            bfr[ni] = *(const bf16x8*)(Bs + (wc + ni * 16 + l15) * 32 + l4 * 8);
        #pragma unroll
        for (int mi = 0; mi < 4; ++mi)
            #pragma unroll
            for (int ni = 0; ni < 4; ++ni)
                acc[mi][ni] = __builtin_amdgcn_mfma_f32_16x16x32_bf16(af[mi], bfr[ni], acc[mi][ni], 0, 0, 0);
    }

    #pragma unroll
    for (int mi = 0; mi < 4; ++mi) {
        const int row0 = mb + wr + mi * 16 + l4 * 4;
        #pragma unroll
        for (int ni = 0; ni < 4; ++ni) {
            const int colg = nb + wc + ni * 16 + l15;
            const float bv = biascat[colg];
            float v[4];
            #pragma unroll
            for (int r = 0; r < 4; ++r) v[r] = acc[mi][ni][r] + bv;

            if (which == 0) {
                if (by < 4) {
                    #pragma unroll
                    for (int r = 0; r < 4; ++r) {
                        outF[(size_t)(row0 + r) * 512 + colg] = v[r];
                        outB0[(size_t)(row0 + r) * 512 + colg] = f2bf(v[r]);
                    }
                } else if (by < 8) {
                    const int c2 = colg - 512;
                    #pragma unroll
                    for (int r = 0; r < 4; ++r)
                        outB1[(size_t)(row0 + r) * 512 + c2] = f2bf(v[r]);
                } else {
                    const int cloc = colg - 1024, i2 = cloc & 31, h2 = cloc >> 5;
                    const float pbv = biascat[colg ^ 16];
                    const bool lo = (ni & 1) == 0;
                    #pragma unroll
                    for (int r = 0; r < 4; ++r) {
                        float vp = acc[mi][ni ^ 1][r] + pbv;
                        int t = (row0 + r) & 2047;
                        float cc_ = cs[t * 16 + (i2 & 15)], ss_ = sn[t * 16 + (i2 & 15)];
                        float o = lo ? (v[r] * cc_ - vp * ss_) : (v[r] * cc_ + vp * ss_);
                        outRope[(size_t)(row0 + r) * 512 + cloc] = o;
                        outB0k[(size_t)(row0 + r) * 2048 + h2 * 128 + 96 + i2] = f2bf(o);
                    }
                }
            } else if (which == 1) {
                if (by < 12) {
                    const int ocol = (colg / 96) * 128 + colg % 96;
                    #pragma unroll
                    for (int r = 0; r < 4; ++r)
                        outB0[(size_t)(row0 + r) * 2048 + ocol] = f2bf(v[r]);
                } else {
                    const int c2 = colg - 1536;
                    ushort4 pv;
                    pv.x = f2bf(v[0]); pv.y = f2bf(v[1]); pv.z = f2bf(v[2]); pv.w = f2bf(v[3]);
                    *(ushort4*)(outB1 + (size_t)c2 * 4096 + row0) = pv;
                }
            } else if (which == 2) {
                if (by < 12) {
                    const int ocol = (colg / 96) * 128 + colg % 96;
                    #pragma unroll
                    for (int r = 0; r < 4; ++r)
                        outB0[(size_t)(row0 + r) * 2048 + ocol] = f2bf(v[r]);
                } else {
                    const int cloc = colg - 1536, i2 = cloc & 31, h2 = cloc >> 5;
                    const float pbv = biascat[colg ^ 16];
                    const bool lo = (ni & 1) == 0;
                    #pragma unroll
                    for (int r = 0; r < 4; ++r) {
                        float vp = acc[mi][ni ^ 1][r] + pbv;
                        int t = (row0 + r) & 2047;
                        float cc_ = cs[t * 16 + (i2 & 15)], ss_ = sn[t * 16 + (i2 & 15)];
                        float o = lo ? (v[r] * cc_ - vp * ss_) : (v[r] * cc_ + vp * ss_);
                        outB0[(size_t)(row0 + r) * 2048 + h2 * 128 + 96 + i2] = f2bf(o);
                    }
                }
            } else {
                #pragma unroll
                for (int r = 0; r < 4; ++r)
                    outF[(size_t)(row0 + r) * 2048 + colg] = v[r];
            }
        }
    }
}

// ---------- flash attention: swapped-QK^T 32x32 MFMA, in-register softmax ----------
__global__ __launch_bounds__(256, 2) void attn_kernel(const unsigned short* __restrict__ Q,
                                                      const unsigned short* __restrict__ Kb,
                                                      const unsigned short* __restrict__ Vtg,
                                                      unsigned short* __restrict__ O) {
    __shared__ __align__(16) unsigned short Ks[2][64 * 128];  // [key][d ^ ((key&7)<<3)]
    __shared__ __align__(16) unsigned short Vs[2][128 * 64];  // [d][k ^ ((d&7)<<3)]

    const int tid = threadIdx.x, w = tid >> 6, lane = tid & 63;
    const int l31 = lane & 31, hi = lane >> 5;
    const int bh = blockIdx.y, b = bh >> 4, h = bh & 15;
    const int qrow = blockIdx.x * 128 + w * 32 + l31;
    const float sl2e = 0.08838834764831845f * 1.4426950408889634f;  // scale*log2e

    bf16x8 qf[8];
    const unsigned short* qptr = Q + (size_t)(b * 2048 + qrow) * 2048 + h * 128 + hi * 8;
    #pragma unroll
    for (int s = 0; s < 8; ++s) qf[s] = *(const bf16x8*)(qptr + s * 16);

    f32x16 acc[4] = {};
    float m_run = -1e30f, l_run = 0.0f;

    const int kl15 = lane >> 4, kd0 = lane & 15;
    const int vr = lane >> 3, vk = lane & 7;

    auto STAGE = [&](int buf, int kt) {
        #pragma unroll
        for (int i = 0; i < 4; ++i) {
            int c = w * 4 + i;
            int key = c * 4 + kl15;
            int d0 = (kd0 * 8) ^ ((key & 7) << 3);
            gload16(Kb + (size_t)(b * 2048 + kt + key) * 2048 + h * 128 + d0, &Ks[buf][c * 512]);
            int dv = c * 8 + vr;
            int k0 = (vk * 8) ^ ((dv & 7) << 3);
            gload16(Vtg + (size_t)(h * 128 + dv) * 4096 + b * 2048 + kt + k0, &Vs[buf][c * 512]);
        }
    };

    STAGE(0, 0);
    __syncthreads();

    for (int t = 0; t < 32; ++t) {
        const int buf = t & 1;
        if (t < 31) STAGE(buf ^ 1, (t + 1) * 64);

        #pragma unroll
        for (int g = 0; g < 2; ++g) {
            const int key = g * 32 + l31;
            const unsigned short* kbase = &Ks[buf][key * 128];
            const int ksw = (key & 7) << 3;
            f32x16 sc = {};
            __builtin_amdgcn_s_setprio(1);
            #pragma unroll
            for (int s = 0; s < 8; ++s) {
                bf16x8 kf = *(const bf16x8*)(kbase + ((s * 16 + hi * 8) ^ ksw));
                sc = __builtin_amdgcn_mfma_f32_32x32x16_bf16(kf, qf[s], sc, 0, 0, 0);
            }
            __builtin_amdgcn_s_setprio(0);

            float pm = sc[0];
            #pragma unroll
            for (int i = 1; i < 16; ++i) pm = fmaxf(pm, sc[i]);
            pm = fmaxf(pm, __shfl_xor(pm, 32, 64));

            if (__any(pm > m_run + 90.51f)) {
                float mn = fmaxf(m_run, pm);
                float f = exp2f((m_run - mn) * sl2e);
                m_run = mn;
                l_run *= f;
                #pragma unroll
                for (int dg = 0; dg < 4; ++dg)
                    #pragma unroll
                    for (int i = 0; i < 16; ++i) acc[dg][i] *= f;
            }
            const float mexp2 = m_run * sl2e;

            float rs = 0.0f;
            #pragma unroll
            for (int s2 = 0; s2 < 2; ++s2) {
                float e[8];
                #pragma unroll
                for (int j = 0; j < 8; ++j) {
                    e[j] = exp2f(fmaf(sc[s2 * 8 + j], sl2e, -mexp2));
                    rs += e[j];
                }
                unsigned X0 = cvtpk_bf16(e[0], e[1]), X1 = cvtpk_bf16(e[2], e[3]);
                unsigned Y0 = cvtpk_bf16(e[4], e[5]), Y1 = cvtpk_bf16(e[6], e[7]);
                pl32swap(X0, Y0);
                pl32swap(X1, Y1);
                union { unsigned u[4]; bf16x8 v; } pf;
                pf.u[0] = X0; pf.u[1] = X1; pf.u[2] = Y0; pf.u[3] = Y1;

                const int kofs = g * 32 + s2 * 16 + hi * 8;
                __builtin_amdgcn_s_setprio(1);
                #pragma unroll
                for (int dg = 0; dg < 4; ++dg) {
                    const int d = dg * 32 + l31;
                    bf16x8 vf = *(const bf16x8*)(&Vs[buf][d * 64 + (kofs ^ ((d & 7) << 3))]);
                    acc[dg] = __builtin_amdgcn_mfma_f32_32x32x16_bf16(vf, pf.v, acc[dg], 0, 0, 0);
                }
                __builtin_amdgcn_s_setprio(0);
            }
            rs += __shfl_xor(rs, 32, 64);
            l_run += rs;
        }
        __syncthreads();
    }

    const float inv = 1.0f / l_run;
    unsigned short* obase = O + (size_t)(b * 2048 + qrow) * 2048 + h * 128;
    #pragma unroll
    for (int dg = 0; dg < 4; ++dg)
        #pragma unroll
        for (int k = 0; k < 4; ++k) {
            ushort4 pv;
            pv.x = f2bf(acc[dg][4 * k + 0] * inv);
            pv.y = f2bf(acc[dg][4 * k + 1] * inv);
            pv.z = f2bf(acc[dg][4 * k + 2] * inv);
            pv.w = f2bf(acc[dg][4 * k + 3] * inv);
            *(ushort4*)(obase + dg * 32 + k * 8 + hi * 4) = pv;
        }
}

extern "C" void kernel_launch(void* const* d_in, const int* in_sizes, int n_in,
                              void* d_out, int out_size, void* d_ws, size_t ws_size,
                              hipStream_t stream) {
    (void)in_sizes; (void)n_in; (void)out_size; (void)ws_size;

    const float* input  = (const float*)d_in[0];
    const float* Wdkv_w = (const float*)d_in[3];
    const float* Wdkv_b = (const float*)d_in[4];
    const float* Wdq_w  = (const float*)d_in[5];
    const float* Wdq_b  = (const float*)d_in[6];
    const float* Wuk_w  = (const float*)d_in[7];
    const float* Wuk_b  = (const float*)d_in[8];
    const float* Wuv_w  = (const float*)d_in[9];
    const float* Wuv_b  = (const float*)d_in[10];
    const float* Wuq_w  = (const float*)d_in[11];
    const float* Wuq_b  = (const float*)d_in[12];
    const float* Wqr_w  = (const float*)d_in[13];
    const float* Wqr_b  = (const float*)d_in[14];
    const float* Wkr_w  = (const float*)d_in[15];
    const float* Wkr_b  = (const float*)d_in[16];
    const float* Wo_w   = (const float*)d_in[17];
    const float* Wo_b   = (const float*)d_in[18];

    float* out_main = (float*)d_out;                       // [4096][2048]
    float* out_ckv  = out_main + (size_t)NROWS * DM;       // [4096][512]
    float* out_krot = out_ckv + (size_t)NROWS * LAT;       // [4096][512]

    char* p = (char*)d_ws;
    auto alloc = [&](size_t bytes) { char* r = p; p += (bytes + 255) & ~(size_t)255; return r; };
    unsigned short* x_bf  = (unsigned short*)alloc((size_t)NROWS * DM * 2);
    unsigned short* w1_t  = (unsigned short*)alloc((size_t)1536 * DM * 2);   // [dkv|dq|kr] x 2048
    unsigned short* w2_t  = (unsigned short*)alloc((size_t)3584 * LAT * 2);  // [uk|uv] x 512
    unsigned short* w3_t  = (unsigned short*)alloc((size_t)2048 * LAT * 2);  // [uq|qr] x 512
    unsigned short* w4_t  = (unsigned short*)alloc((size_t)DM * DM * 2);     // wo
    unsigned short* ckv_bf = (unsigned short*)alloc((size_t)NROWS * LAT * 2);
    unsigned short* cq_bf  = (unsigned short*)alloc((size_t)NROWS * LAT * 2);
    unsigned short* q_bf   = (unsigned short*)alloc((size_t)NROWS * DM * 2);
    unsigned short* k_bf   = (unsigned short*)alloc((size_t)NROWS * DM * 2);
    unsigned short* vt_g   = (unsigned short*)alloc((size_t)DM * NROWS * 2); // V^T [2048][4096]
    unsigned short* ao_bf  = (unsigned short*)alloc((size_t)NROWS * DM * 2);
    float* cos_t = (float*)alloc((size_t)2048 * 16 * 4);
    float* sin_t = (float*)alloc((size_t)2048 * 16 * 4);
    float* bc1 = (float*)alloc(1536 * 4);
    float* bc2 = (float*)alloc(3584 * 4);
    float* bc3 = (float*)alloc(2048 * 4);
    float* bc4 = (float*)alloc(2048 * 4);

    // input -> bf16
    f32_to_bf16_kernel<<<(NROWS * DM) / (256 * 4), 256, 0, stream>>>(input, x_bf, NROWS * DM);

    // weights -> transposed bf16, packed into fused layouts
    auto tw = [&](const float* W, unsigned short* Wt, int K, int N) {
        transpose_w_kernel<<<dim3(N / 32, K / 32), dim3(32, 8), 0, stream>>>(W, Wt, K, N);
    };
    tw(Wdkv_w, w1_t,                2048, 512);
    tw(Wdq_w,  w1_t + 512 * 2048,   2048, 512);
    tw(Wkr_w,  w1_t + 1024 * 2048,  2048, 512);
    tw(Wuk_w,  w2_t,                512, 1536);
    tw(Wuv_w,  w2_t + 1536 * 512,   512, 2048);
    tw(Wuq_w,  w3_t,                512, 1536);
    tw(Wqr_w,  w3_t + 1536 * 512,   512, 512);
    tw(Wo_w,   w4_t,                2048, 2048);

    rope_table_kernel<<<(2048 * 16) / 256, 256, 0, stream>>>(cos_t, sin_t);

    // concatenated biases (d2d copies)
    hipMemcpyAsync(bc1,        Wdkv_b, 512 * 4,  hipMemcpyDeviceToDevice, stream);
    hipMemcpyAsync(bc1 + 512,  Wdq_b,  512 * 4,  hipMemcpyDeviceToDevice, stream);
    hipMemcpyAsync(bc1 + 1024, Wkr_b,  512 * 4,  hipMemcpyDeviceToDevice, stream);
    hipMemcpyAsync(bc2,        Wuk_b,  1536 * 4, hipMemcpyDeviceToDevice, stream);
    hipMemcpyAsync(bc2 + 1536, Wuv_b,  2048 * 4, hipMemcpyDeviceToDevice, stream);
    hipMemcpyAsync(bc3,        Wuq_b,  1536 * 4, hipMemcpyDeviceToDevice, stream);
    hipMemcpyAsync(bc3 + 1536, Wqr_b,  512 * 4,  hipMemcpyDeviceToDevice, stream);
    hipMemcpyAsync(bc4,        Wo_b,   2048 * 4, hipMemcpyDeviceToDevice, stream);

    // G1: x @ [Wdkv|Wdq|Wkr] -> c_kv(f32+bf16), c_q(bf16), k_rot(rope: f32 out + k cols 96..127)
    gemm_fused_kernel<<<dim3(32, 12), 256, 0, stream>>>(x_bf, w1_t, bc1, 2048, 0,
                                                        out_ckv, ckv_bf, cq_bf, k_bf, out_krot, cos_t, sin_t);
    // G2: ckv @ [Wuk|Wuv] -> k_base(remap into k_bf), V^T
    gemm_fused_kernel<<<dim3(32, 28), 256, 0, stream>>>(ckv_bf, w2_t, bc2, 512, 1,
                                                        nullptr, k_bf, vt_g, nullptr, nullptr, nullptr, nullptr);
    // G3: cq @ [Wuq|Wqr] -> q_base(remap) + q_rot(rope) into q_bf
    gemm_fused_kernel<<<dim3(32, 16), 256, 0, stream>>>(cq_bf, w3_t, bc3, 512, 2,
                                                        nullptr, q_bf, nullptr, nullptr, nullptr, cos_t, sin_t);

    // attention
    attn_kernel<<<dim3(16, 2 * NH), 256, 0, stream>>>(q_bf, k_bf, vt_g, ao_bf);

    // G4: output projection
    gemm_fused_kernel<<<dim3(32, 16), 256, 0, stream>>>(ao_bf, w4_t, bc4, 2048, 3,
                                                        out_main, nullptr, nullptr, nullptr, nullptr, nullptr, nullptr);
}

// Round 5
// 258.954 us; speedup vs baseline: 2.8783x; 1.1640x over previous
//
#include <hip/hip_runtime.h>

typedef __bf16 bf16x8 __attribute__((ext_vector_type(8)));
typedef float f32x4 __attribute__((ext_vector_type(4)));
typedef float f32x16 __attribute__((ext_vector_type(16)));

#define NROWS 4096   // B*T
#define DM 2048
#define LAT 512
#define NH 16
#define DH 128

__device__ __forceinline__ unsigned short f2bf(float f) {
    union { float f; unsigned u; } v; v.f = f;
    unsigned r = v.u + 0x7fffu + ((v.u >> 16) & 1u);
    return (unsigned short)(r >> 16);
}
__device__ __forceinline__ void gload16(const void* g, void* l) {
    __builtin_amdgcn_global_load_lds((const __attribute__((address_space(1))) unsigned int*)g,
                                     (__attribute__((address_space(3))) unsigned int*)l, 16, 0, 0);
}
__device__ __forceinline__ unsigned cvtpk_bf16(float lo, float hi) {
    unsigned r;
    asm("v_cvt_pk_bf16_f32 %0, %1, %2" : "=v"(r) : "v"(lo), "v"(hi));
    return r;
}
__device__ __forceinline__ void pl32swap(unsigned& a, unsigned& b) {
    asm("v_permlane32_swap_b32 %0, %1" : "+v"(a), "+v"(b));
}
// raw v_exp_f32 (2^x) — avoids __ocml_exp2_f32's denormal fixup (R4 regression)
__device__ __forceinline__ float exp2a(float x) {
    float r;
    asm("v_exp_f32 %0, %1" : "=v"(r) : "v"(x));
    return r;
}

// ---------- consolidated prep: 8 weight transposes + x->bf16 + rope table + bias concat ----------
struct PrepParams {
    const float* tsrc[8]; unsigned short* tdst[8];
    int tK[8]; int tN[8]; int tstart[8];
    const float* input; unsigned short* xbf;
    float* cs; float* sn;
    const float* bsrc[8]; float* bdst[8]; int blen[8];
};

#define PREP_T_END   9984
#define PREP_X_END   18176
#define PREP_R_END   18304
#define PREP_B_END   18340

__global__ __launch_bounds__(256) void prep_kernel(PrepParams P) {
    const int bid = blockIdx.x, tid = threadIdx.x;
    if (bid < PREP_T_END) {
        // weight transpose+convert: W[K][N] f32 -> Wt[N][K] bf16
        int j = 0;
        #pragma unroll
        for (int i = 1; i < 8; ++i) if (bid >= P.tstart[i]) j = i;
        const int local = bid - P.tstart[j];
        const float* W = P.tsrc[j];
        unsigned short* Wt = P.tdst[j];
        const int K = P.tK[j], N = P.tN[j];
        const int nbx = N >> 5;
        const int nb = (local % nbx) * 32, kb = (local / nbx) * 32;
        __shared__ float tile[32][33];
        const int tx = tid & 31, ty = tid >> 5;
        #pragma unroll
        for (int i = 0; i < 32; i += 8)
            tile[ty + i][tx] = W[(size_t)(kb + ty + i) * N + nb + tx];
        __syncthreads();
        #pragma unroll
        for (int i = 0; i < 32; i += 8)
            Wt[(size_t)(nb + ty + i) * K + kb + tx] = f2bf(tile[tx][ty + i]);
    } else if (bid < PREP_X_END) {
        // x f32 -> bf16
        const int i = ((bid - PREP_T_END) * 256 + tid) * 4;
        float4 v = *(const float4*)(P.input + i);
        unsigned short* y = P.xbf + i;
        y[0] = f2bf(v.x); y[1] = f2bf(v.y); y[2] = f2bf(v.z); y[3] = f2bf(v.w);
    } else if (bid < PREP_R_END) {
        // rope cos/sin table [2048][16]
        const int idx = (bid - PREP_X_END) * 256 + tid;
        const int i = idx & 15, t = idx >> 4;
        float inv = powf(10000.0f, -(float)i / 16.0f);
        float a = (float)t * inv;
        P.cs[idx] = cosf(a);
        P.sn[idx] = sinf(a);
    } else {
        // bias concat
        const int gid = (bid - PREP_R_END) * 256 + tid;
        int off = 0;
        #pragma unroll
        for (int i = 0; i < 8; ++i) {
            if (gid >= off && gid < off + P.blen[i])
                P.bdst[i][gid - off] = P.bsrc[i][gid - off];
            off += P.blen[i];
        }
    }
}

// ---------- fused bf16 GEMM: C[M][Nfused] = A[M][K] @ Bt[Nfused][K]^T + biascat ----------
// m97 structure: 128x128 tile, 4 waves 2x2, linear LDS [row][32], gload_lds staging.
//  which=0 (G1, N=1536): by<4 -> c_kv (f32 outF + bf16 outB0); by<8 -> c_q (outB1);
//                        else -> k_rot: RoPE -> outRope (f32) + k heads cols 96..127 (outB0k)
//  which=1 (G2, N=3584): by<12 -> k_base 96->128 remap (outB0); else -> V^T via LDS bounce (outB1)
//  which=2 (G3, N=2048): by<12 -> q_base remap (outB0); else -> q_rot RoPE -> q cols 96..127
//  which=3 (G4, N=2048): outF = final output (f32)
__global__ __launch_bounds__(256) void gemm_fused_kernel(const unsigned short* __restrict__ A,
                                                         const unsigned short* __restrict__ Bt,
                                                         const float* __restrict__ biascat,
                                                         int K, int which,
                                                         float* __restrict__ outF,
                                                         unsigned short* __restrict__ outB0,
                                                         unsigned short* __restrict__ outB1,
                                                         unsigned short* __restrict__ outB0k,
                                                         float* __restrict__ outRope,
                                                         const float* __restrict__ cs,
                                                         const float* __restrict__ sn) {
    __shared__ __align__(16) unsigned short SM[9216];  // As(4096) | Bs(4096); reused as 128x72 bounce tile
    unsigned short* As = SM;
    unsigned short* Bs = SM + 4096;
    const int tid = threadIdx.x;
    const int mb = blockIdx.x * 128;
    const int by = blockIdx.y, nb = by * 128;
    const int w = tid >> 6, lane = tid & 63;
    const int wr = (w >> 1) * 64, wc = (w & 1) * 64;
    const int l15 = lane & 15, l4 = lane >> 4;
    const int srow = lane >> 2, sko = (lane & 3) * 8;

    f32x4 acc[4][4] = {};

    for (int k0 = 0; k0 < K; k0 += 32) {
        __syncthreads();
        #pragma unroll
        for (int c = 0; c < 16; c += 4) {
            int cc = c + w;
            if (cc < 8)
                gload16(A + (size_t)(mb + cc * 16 + srow) * K + k0 + sko, As + cc * 512);
            else
                gload16(Bt + (size_t)(nb + (cc - 8) * 16 + srow) * K + k0 + sko, Bs + (cc - 8) * 512);
        }
        __syncthreads();
        bf16x8 af[4], bfr[4];
        #pragma unroll
        for (int mi = 0; mi < 4; ++mi)
            af[mi] = *(const bf16x8*)(As + (wr + mi * 16 + l15) * 32 + l4 * 8);
        #pragma unroll
        for (int ni = 0; ni < 4; ++ni)
            bfr[ni] = *(const bf16x8*)(Bs + (wc + ni * 16 + l15) * 32 + l4 * 8);
        #pragma unroll
        for (int mi = 0; mi < 4; ++mi)
            #pragma unroll
            for (int ni = 0; ni < 4; ++ni)
                acc[mi][ni] = __builtin_amdgcn_mfma_f32_16x16x32_bf16(af[mi], bfr[ni], acc[mi][ni], 0, 0, 0);
    }

    if (which == 1 && by >= 12) {
        // ---- V^T via LDS bounce: coalesced 16B stores along token dim ----
        const int c2b = nb - 1536;   // v-dim base
        #pragma unroll
        for (int half = 0; half < 2; ++half) {
            __syncthreads();
            if ((wr >> 6) == half) {
                #pragma unroll
                for (int mi = 0; mi < 4; ++mi)
                    #pragma unroll
                    for (int ni = 0; ni < 4; ++ni) {
                        const int col = wc + ni * 16 + l15;       // v-dim within tile
                        const float bv = biascat[nb + col];
                        ushort4 pv;
                        pv.x = f2bf(acc[mi][ni][0] + bv);
                        pv.y = f2bf(acc[mi][ni][1] + bv);
                        pv.z = f2bf(acc[mi][ni][2] + bv);
                        pv.w = f2bf(acc[mi][ni][3] + bv);
                        *(ushort4*)(SM + col * 72 + mi * 16 + l4 * 4) = pv;
                    }
            }
            __syncthreads();
            const int c = tid >> 1;
            #pragma unroll
            for (int j = 0; j < 4; ++j) {
                const int seg = (tid & 1) * 4 + j;
                uint4 val = *(const uint4*)(SM + c * 72 + seg * 8);
                *(uint4*)(outB1 + (size_t)(c2b + c) * 4096 + mb + half * 64 + seg * 8) = val;
            }
        }
        return;
    }

    #pragma unroll
    for (int mi = 0; mi < 4; ++mi) {
        const int row0 = mb + wr + mi * 16 + l4 * 4;
        #pragma unroll
        for (int ni = 0; ni < 4; ++ni) {
            const int colg = nb + wc + ni * 16 + l15;
            const float bv = biascat[colg];
            float v[4];
            #pragma unroll
            for (int r = 0; r < 4; ++r) v[r] = acc[mi][ni][r] + bv;

            if (which == 0) {
                if (by < 4) {
                    #pragma unroll
                    for (int r = 0; r < 4; ++r) {
                        outF[(size_t)(row0 + r) * 512 + colg] = v[r];
                        outB0[(size_t)(row0 + r) * 512 + colg] = f2bf(v[r]);
                    }
                } else if (by < 8) {
                    const int c2 = colg - 512;
                    #pragma unroll
                    for (int r = 0; r < 4; ++r)
                        outB1[(size_t)(row0 + r) * 512 + c2] = f2bf(v[r]);
                } else {
                    const int cloc = colg - 1024, i2 = cloc & 31, h2 = cloc >> 5;
                    const float pbv = biascat[colg ^ 16];
                    const bool lo = (ni & 1) == 0;
                    #pragma unroll
                    for (int r = 0; r < 4; ++r) {
                        float vp = acc[mi][ni ^ 1][r] + pbv;
                        int t = (row0 + r) & 2047;
                        float cc_ = cs[t * 16 + (i2 & 15)], ss_ = sn[t * 16 + (i2 & 15)];
                        float o = lo ? (v[r] * cc_ - vp * ss_) : (v[r] * cc_ + vp * ss_);
                        outRope[(size_t)(row0 + r) * 512 + cloc] = o;
                        outB0k[(size_t)(row0 + r) * 2048 + h2 * 128 + 96 + i2] = f2bf(o);
                    }
                }
            } else if (which == 1) {
                const int ocol = (colg / 96) * 128 + colg % 96;
                #pragma unroll
                for (int r = 0; r < 4; ++r)
                    outB0[(size_t)(row0 + r) * 2048 + ocol] = f2bf(v[r]);
            } else if (which == 2) {
                if (by < 12) {
                    const int ocol = (colg / 96) * 128 + colg % 96;
                    #pragma unroll
                    for (int r = 0; r < 4; ++r)
                        outB0[(size_t)(row0 + r) * 2048 + ocol] = f2bf(v[r]);
                } else {
                    const int cloc = colg - 1536, i2 = cloc & 31, h2 = cloc >> 5;
                    const float pbv = biascat[colg ^ 16];
                    const bool lo = (ni & 1) == 0;
                    #pragma unroll
                    for (int r = 0; r < 4; ++r) {
                        float vp = acc[mi][ni ^ 1][r] + pbv;
                        int t = (row0 + r) & 2047;
                        float cc_ = cs[t * 16 + (i2 & 15)], ss_ = sn[t * 16 + (i2 & 15)];
                        float o = lo ? (v[r] * cc_ - vp * ss_) : (v[r] * cc_ + vp * ss_);
                        outB0[(size_t)(row0 + r) * 2048 + h2 * 128 + 96 + i2] = f2bf(o);
                    }
                }
            } else {
                #pragma unroll
                for (int r = 0; r < 4; ++r)
                    outF[(size_t)(row0 + r) * 2048 + colg] = v[r];
            }
        }
    }
}

// ---------- flash attention: swapped-QK^T 32x32 MFMA, in-register softmax ----------
__global__ __launch_bounds__(256, 2) void attn_kernel(const unsigned short* __restrict__ Q,
                                                      const unsigned short* __restrict__ Kb,
                                                      const unsigned short* __restrict__ Vtg,
                                                      unsigned short* __restrict__ O) {
    __shared__ __align__(16) unsigned short Ks[2][64 * 128];  // [key][d ^ ((key&7)<<3)]
    __shared__ __align__(16) unsigned short Vs[2][128 * 64];  // [d][k ^ ((d&7)<<3)]

    const int tid = threadIdx.x, w = tid >> 6, lane = tid & 63;
    const int l31 = lane & 31, hi = lane >> 5;
    const int bh = blockIdx.y, b = bh >> 4, h = bh & 15;
    const int qrow = blockIdx.x * 128 + w * 32 + l31;
    const float sl2e = 0.08838834764831845f * 1.4426950408889634f;  // scale*log2e

    bf16x8 qf[8];
    const unsigned short* qptr = Q + (size_t)(b * 2048 + qrow) * 2048 + h * 128 + hi * 8;
    #pragma unroll
    for (int s = 0; s < 8; ++s) qf[s] = *(const bf16x8*)(qptr + s * 16);

    f32x16 acc[4] = {};
    float m_run = -1e30f, l_run = 0.0f;

    const int kl15 = lane >> 4, kd0 = lane & 15;
    const int vr = lane >> 3, vk = lane & 7;

    auto STAGE = [&](int buf, int kt) {
        #pragma unroll
        for (int i = 0; i < 4; ++i) {
            int c = w * 4 + i;
            int key = c * 4 + kl15;
            int d0 = (kd0 * 8) ^ ((key & 7) << 3);
            gload16(Kb + (size_t)(b * 2048 + kt + key) * 2048 + h * 128 + d0, &Ks[buf][c * 512]);
            int dv = c * 8 + vr;
            int k0 = (vk * 8) ^ ((dv & 7) << 3);
            gload16(Vtg + (size_t)(h * 128 + dv) * 4096 + b * 2048 + kt + k0, &Vs[buf][c * 512]);
        }
    };

    STAGE(0, 0);
    __syncthreads();

    for (int t = 0; t < 32; ++t) {
        const int buf = t & 1;
        if (t < 31) STAGE(buf ^ 1, (t + 1) * 64);

        #pragma unroll
        for (int g = 0; g < 2; ++g) {
            const int key = g * 32 + l31;
            const unsigned short* kbase = &Ks[buf][key * 128];
            const int ksw = (key & 7) << 3;
            f32x16 sc = {};
            __builtin_amdgcn_s_setprio(1);
            #pragma unroll
            for (int s = 0; s < 8; ++s) {
                bf16x8 kf = *(const bf16x8*)(kbase + ((s * 16 + hi * 8) ^ ksw));
                sc = __builtin_amdgcn_mfma_f32_32x32x16_bf16(kf, qf[s], sc, 0, 0, 0);
            }
            __builtin_amdgcn_s_setprio(0);

            float pm = sc[0];
            #pragma unroll
            for (int i = 1; i < 16; ++i) pm = fmaxf(pm, sc[i]);
            pm = fmaxf(pm, __shfl_xor(pm, 32, 64));

            if (__any(pm > m_run + 90.51f)) {
                float mn = fmaxf(m_run, pm);
                float f = exp2a((m_run - mn) * sl2e);
                m_run = mn;
                l_run *= f;
                #pragma unroll
                for (int dg = 0; dg < 4; ++dg)
                    #pragma unroll
                    for (int i = 0; i < 16; ++i) acc[dg][i] *= f;
            }
            const float mexp2 = m_run * sl2e;

            float rs = 0.0f;
            #pragma unroll
            for (int s2 = 0; s2 < 2; ++s2) {
                float e[8];
                #pragma unroll
                for (int j = 0; j < 8; ++j) {
                    e[j] = exp2a(fmaf(sc[s2 * 8 + j], sl2e, -mexp2));
                    rs += e[j];
                }
                unsigned X0 = cvtpk_bf16(e[0], e[1]), X1 = cvtpk_bf16(e[2], e[3]);
                unsigned Y0 = cvtpk_bf16(e[4], e[5]), Y1 = cvtpk_bf16(e[6], e[7]);
                pl32swap(X0, Y0);
                pl32swap(X1, Y1);
                union { unsigned u[4]; bf16x8 v; } pf;
                pf.u[0] = X0; pf.u[1] = X1; pf.u[2] = Y0; pf.u[3] = Y1;

                const int kofs = g * 32 + s2 * 16 + hi * 8;
                __builtin_amdgcn_s_setprio(1);
                #pragma unroll
                for (int dg = 0; dg < 4; ++dg) {
                    const int d = dg * 32 + l31;
                    bf16x8 vf = *(const bf16x8*)(&Vs[buf][d * 64 + (kofs ^ ((d & 7) << 3))]);
                    acc[dg] = __builtin_amdgcn_mfma_f32_32x32x16_bf16(vf, pf.v, acc[dg], 0, 0, 0);
                }
                __builtin_amdgcn_s_setprio(0);
            }
            rs += __shfl_xor(rs, 32, 64);
            l_run += rs;
        }
        __syncthreads();
    }

    const float inv = 1.0f / l_run;
    unsigned short* obase = O + (size_t)(b * 2048 + qrow) * 2048 + h * 128;
    #pragma unroll
    for (int dg = 0; dg < 4; ++dg)
        #pragma unroll
        for (int k = 0; k < 4; ++k) {
            ushort4 pv;
            pv.x = f2bf(acc[dg][4 * k + 0] * inv);
            pv.y = f2bf(acc[dg][4 * k + 1] * inv);
            pv.z = f2bf(acc[dg][4 * k + 2] * inv);
            pv.w = f2bf(acc[dg][4 * k + 3] * inv);
            *(ushort4*)(obase + dg * 32 + k * 8 + hi * 4) = pv;
        }
}

extern "C" void kernel_launch(void* const* d_in, const int* in_sizes, int n_in,
                              void* d_out, int out_size, void* d_ws, size_t ws_size,
                              hipStream_t stream) {
    (void)in_sizes; (void)n_in; (void)out_size; (void)ws_size;

    const float* input  = (const float*)d_in[0];
    const float* Wdkv_w = (const float*)d_in[3];
    const float* Wdkv_b = (const float*)d_in[4];
    const float* Wdq_w  = (const float*)d_in[5];
    const float* Wdq_b  = (const float*)d_in[6];
    const float* Wuk_w  = (const float*)d_in[7];
    const float* Wuk_b  = (const float*)d_in[8];
    const float* Wuv_w  = (const float*)d_in[9];
    const float* Wuv_b  = (const float*)d_in[10];
    const float* Wuq_w  = (const float*)d_in[11];
    const float* Wuq_b  = (const float*)d_in[12];
    const float* Wqr_w  = (const float*)d_in[13];
    const float* Wqr_b  = (const float*)d_in[14];
    const float* Wkr_w  = (const float*)d_in[15];
    const float* Wkr_b  = (const float*)d_in[16];
    const float* Wo_w   = (const float*)d_in[17];
    const float* Wo_b   = (const float*)d_in[18];

    float* out_main = (float*)d_out;                       // [4096][2048]
    float* out_ckv  = out_main + (size_t)NROWS * DM;       // [4096][512]
    float* out_krot = out_ckv + (size_t)NROWS * LAT;       // [4096][512]

    char* p = (char*)d_ws;
    auto alloc = [&](size_t bytes) { char* r = p; p += (bytes + 255) & ~(size_t)255; return r; };
    unsigned short* x_bf  = (unsigned short*)alloc((size_t)NROWS * DM * 2);
    unsigned short* w1_t  = (unsigned short*)alloc((size_t)1536 * DM * 2);   // [dkv|dq|kr] x 2048
    unsigned short* w2_t  = (unsigned short*)alloc((size_t)3584 * LAT * 2);  // [uk|uv] x 512
    unsigned short* w3_t  = (unsigned short*)alloc((size_t)2048 * LAT * 2);  // [uq|qr] x 512
    unsigned short* w4_t  = (unsigned short*)alloc((size_t)DM * DM * 2);     // wo
    unsigned short* ckv_bf = (unsigned short*)alloc((size_t)NROWS * LAT * 2);
    unsigned short* cq_bf  = (unsigned short*)alloc((size_t)NROWS * LAT * 2);
    unsigned short* q_bf   = (unsigned short*)alloc((size_t)NROWS * DM * 2);
    unsigned short* k_bf   = (unsigned short*)alloc((size_t)NROWS * DM * 2);
    unsigned short* vt_g   = (unsigned short*)alloc((size_t)DM * NROWS * 2); // V^T [2048][4096]
    unsigned short* ao_bf  = (unsigned short*)alloc((size_t)NROWS * DM * 2);
    float* cos_t = (float*)alloc((size_t)2048 * 16 * 4);
    float* sin_t = (float*)alloc((size_t)2048 * 16 * 4);
    float* bc1 = (float*)alloc(1536 * 4);
    float* bc2 = (float*)alloc(3584 * 4);
    float* bc3 = (float*)alloc(2048 * 4);
    float* bc4 = (float*)alloc(2048 * 4);

    // ---- single prep dispatch ----
    PrepParams P;
    const float* tsrc[8] = {Wdkv_w, Wdq_w, Wkr_w, Wuk_w, Wuv_w, Wuq_w, Wqr_w, Wo_w};
    unsigned short* tdst[8] = {w1_t, w1_t + 512 * 2048, w1_t + 1024 * 2048,
                               w2_t, w2_t + 1536 * 512, w3_t, w3_t + 1536 * 512, w4_t};
    int tK[8] = {2048, 2048, 2048, 512, 512, 512, 512, 2048};
    int tN[8] = {512, 512, 512, 1536, 2048, 1536, 512, 2048};
    int tstart[8] = {0, 1024, 2048, 3072, 3840, 4864, 5632, 5888};  // counts: 1024,1024,1024,768,1024,768,256,4096
    const float* bsrc[8] = {Wdkv_b, Wdq_b, Wkr_b, Wuk_b, Wuv_b, Wuq_b, Wqr_b, Wo_b};
    float* bdst[8] = {bc1, bc1 + 512, bc1 + 1024, bc2, bc2 + 1536, bc3, bc3 + 1536, bc4};
    int blen[8] = {512, 512, 512, 1536, 2048, 1536, 512, 2048};
    for (int i = 0; i < 8; ++i) {
        P.tsrc[i] = tsrc[i]; P.tdst[i] = tdst[i]; P.tK[i] = tK[i]; P.tN[i] = tN[i];
        P.tstart[i] = tstart[i]; P.bsrc[i] = bsrc[i]; P.bdst[i] = bdst[i]; P.blen[i] = blen[i];
    }
    P.input = input; P.xbf = x_bf; P.cs = cos_t; P.sn = sin_t;
    prep_kernel<<<PREP_B_END, 256, 0, stream>>>(P);

    // G1: x @ [Wdkv|Wdq|Wkr] -> c_kv(f32+bf16), c_q(bf16), k_rot(rope: f32 out + k cols 96..127)
    gemm_fused_kernel<<<dim3(32, 12), 256, 0, stream>>>(x_bf, w1_t, bc1, 2048, 0,
                                                        out_ckv, ckv_bf, cq_bf, k_bf, out_krot, cos_t, sin_t);
    // G2: ckv @ [Wuk|Wuv] -> k_base(remap into k_bf), V^T (LDS-bounce coalesced)
    gemm_fused_kernel<<<dim3(32, 28), 256, 0, stream>>>(ckv_bf, w2_t, bc2, 512, 1,
                                                        nullptr, k_bf, vt_g, nullptr, nullptr, nullptr, nullptr);
    // G3: cq @ [Wuq|Wqr] -> q_base(remap) + q_rot(rope) into q_bf
    gemm_fused_kernel<<<dim3(32, 16), 256, 0, stream>>>(cq_bf, w3_t, bc3, 512, 2,
                                                        nullptr, q_bf, nullptr, nullptr, nullptr, cos_t, sin_t);

    // attention
    attn_kernel<<<dim3(16, 2 * NH), 256, 0, stream>>>(q_bf, k_bf, vt_g, ao_bf);

    // G4: output projection
    gemm_fused_kernel<<<dim3(32, 16), 256, 0, stream>>>(ao_bf, w4_t, bc4, 2048, 3,
                                                        out_main, nullptr, nullptr, nullptr, nullptr, nullptr, nullptr);
}

// Round 6
// 239.004 us; speedup vs baseline: 3.1185x; 1.0835x over previous
//
#include <hip/hip_runtime.h>

typedef __bf16 bf16x8 __attribute__((ext_vector_type(8)));
typedef float f32x4 __attribute__((ext_vector_type(4)));
typedef float f32x16 __attribute__((ext_vector_type(16)));

#define NROWS 4096   // B*T
#define DM 2048
#define LAT 512
#define NH 16
#define DH 128

__device__ __forceinline__ unsigned short f2bf(float f) {
    union { float f; unsigned u; } v; v.f = f;
    unsigned r = v.u + 0x7fffu + ((v.u >> 16) & 1u);
    return (unsigned short)(r >> 16);
}
__device__ __forceinline__ void gload16(const void* g, void* l) {
    __builtin_amdgcn_global_load_lds((const __attribute__((address_space(1))) unsigned int*)g,
                                     (__attribute__((address_space(3))) unsigned int*)l, 16, 0, 0);
}
__device__ __forceinline__ unsigned cvtpk_bf16(float lo, float hi) {
    unsigned r;
    asm("v_cvt_pk_bf16_f32 %0, %1, %2" : "=v"(r) : "v"(lo), "v"(hi));
    return r;
}
__device__ __forceinline__ void pl32swap(unsigned& a, unsigned& b) {
    asm("v_permlane32_swap_b32 %0, %1" : "+v"(a), "+v"(b));
}
// raw v_exp_f32 (2^x) — avoids __ocml_exp2_f32's denormal fixup (R4 regression)
__device__ __forceinline__ float exp2a(float x) {
    float r;
    asm("v_exp_f32 %0, %1" : "=v"(r) : "v"(x));
    return r;
}

// ---------- consolidated prep: 8 weight transposes + x->bf16 + rope table + bias concat ----------
struct PrepParams {
    const float* tsrc[8]; unsigned short* tdst[8];
    int tK[8]; int tN[8]; int tstart[8];
    const float* input; unsigned short* xbf;
    float* cs; float* sn;
    const float* bsrc[8]; float* bdst[8]; int blen[8];
};

#define PREP_T_END   9984
#define PREP_X_END   18176
#define PREP_R_END   18304
#define PREP_B_END   18340

__global__ __launch_bounds__(256) void prep_kernel(PrepParams P) {
    const int bid = blockIdx.x, tid = threadIdx.x;
    if (bid < PREP_T_END) {
        int j = 0;
        #pragma unroll
        for (int i = 1; i < 8; ++i) if (bid >= P.tstart[i]) j = i;
        const int local = bid - P.tstart[j];
        const float* W = P.tsrc[j];
        unsigned short* Wt = P.tdst[j];
        const int K = P.tK[j], N = P.tN[j];
        const int nbx = N >> 5;
        const int nb = (local % nbx) * 32, kb = (local / nbx) * 32;
        __shared__ float tile[32][33];
        const int tx = tid & 31, ty = tid >> 5;
        #pragma unroll
        for (int i = 0; i < 32; i += 8)
            tile[ty + i][tx] = W[(size_t)(kb + ty + i) * N + nb + tx];
        __syncthreads();
        #pragma unroll
        for (int i = 0; i < 32; i += 8)
            Wt[(size_t)(nb + ty + i) * K + kb + tx] = f2bf(tile[tx][ty + i]);
    } else if (bid < PREP_X_END) {
        const int i = ((bid - PREP_T_END) * 256 + tid) * 4;
        float4 v = *(const float4*)(P.input + i);
        unsigned short* y = P.xbf + i;
        y[0] = f2bf(v.x); y[1] = f2bf(v.y); y[2] = f2bf(v.z); y[3] = f2bf(v.w);
    } else if (bid < PREP_R_END) {
        const int idx = (bid - PREP_X_END) * 256 + tid;
        const int i = idx & 15, t = idx >> 4;
        float inv = powf(10000.0f, -(float)i / 16.0f);
        float a = (float)t * inv;
        P.cs[idx] = cosf(a);
        P.sn[idx] = sinf(a);
    } else {
        const int gid = (bid - PREP_R_END) * 256 + tid;
        int off = 0;
        #pragma unroll
        for (int i = 0; i < 8; ++i) {
            if (gid >= off && gid < off + P.blen[i])
                P.bdst[i][gid - off] = P.bsrc[i][gid - off];
            off += P.blen[i];
        }
    }
}

// ---------- fused bf16 GEMM: C[M][Nfused] = A[M][K] @ Bt[Nfused][K]^T + biascat ----------
// m97 structure + LDS double-buffer + counted-vmcnt raw barriers (T3/T4 2-phase).
//  which=0 (G1, N=1536): by<4 -> c_kv (f32 outF + bf16 outB0); by<8 -> c_q (outB1);
//                        else -> k_rot: RoPE -> outRope (f32) + k heads cols 96..127 (outB0k)
//  which=1 (G2, N=3584): by<12 -> k_base 96->128 remap (outB0); else -> V^T via LDS bounce (outB1)
//  which=2 (G3, N=2048): by<12 -> q_base remap (outB0); else -> q_rot RoPE -> q cols 96..127
//  which=3 (G4, N=2048): outF = final output (f32)
__global__ __launch_bounds__(256) void gemm_fused_kernel(const unsigned short* __restrict__ A,
                                                         const unsigned short* __restrict__ Bt,
                                                         const float* __restrict__ biascat,
                                                         int K, int which,
                                                         float* __restrict__ outF,
                                                         unsigned short* __restrict__ outB0,
                                                         unsigned short* __restrict__ outB1,
                                                         unsigned short* __restrict__ outB0k,
                                                         float* __restrict__ outRope,
                                                         const float* __restrict__ cs,
                                                         const float* __restrict__ sn) {
    __shared__ __align__(16) unsigned short SM[2][8192];  // dbuf: As(4096)|Bs(4096); bounce reuses flat
    const int tid = threadIdx.x;
    const int mb = blockIdx.x * 128;
    const int by = blockIdx.y, nb = by * 128;
    const int w = tid >> 6, lane = tid & 63;
    const int wr = (w >> 1) * 64, wc = (w & 1) * 64;
    const int l15 = lane & 15, l4 = lane >> 4;
    const int srow = lane >> 2, sko = (lane & 3) * 8;

    f32x4 acc[4][4] = {};

    // STAGE(buf, k0): 4 gload_lds per wave (2 A-chunks + 2 B-chunks)
    auto STAGE = [&](int buf, int k0) {
        #pragma unroll
        for (int c = 0; c < 16; c += 4) {
            int cc = c + w;
            if (cc < 8)
                gload16(A + (size_t)(mb + cc * 16 + srow) * K + k0 + sko, SM[buf] + cc * 512);
            else
                gload16(Bt + (size_t)(nb + (cc - 8) * 16 + srow) * K + k0 + sko, SM[buf] + 4096 + (cc - 8) * 512);
        }
    };

    const int nk = K >> 5;
    STAGE(0, 0);
    for (int kt = 0; kt < nk; ++kt) {
        const int buf = kt & 1;
        if (kt + 1 < nk) {
            STAGE(buf ^ 1, (kt + 1) << 5);
            asm volatile("s_waitcnt vmcnt(4)" ::: "memory");
        } else {
            asm volatile("s_waitcnt vmcnt(0)" ::: "memory");
        }
        __builtin_amdgcn_sched_barrier(0);
        __builtin_amdgcn_s_barrier();
        __builtin_amdgcn_sched_barrier(0);

        const unsigned short* As = SM[buf];
        const unsigned short* Bs = SM[buf] + 4096;
        bf16x8 af[4], bfr[4];
        #pragma unroll
        for (int mi = 0; mi < 4; ++mi)
            af[mi] = *(const bf16x8*)(As + (wr + mi * 16 + l15) * 32 + l4 * 8);
        #pragma unroll
        for (int ni = 0; ni < 4; ++ni)
            bfr[ni] = *(const bf16x8*)(Bs + (wc + ni * 16 + l15) * 32 + l4 * 8);
        #pragma unroll
        for (int mi = 0; mi < 4; ++mi)
            #pragma unroll
            for (int ni = 0; ni < 4; ++ni)
                acc[mi][ni] = __builtin_amdgcn_mfma_f32_16x16x32_bf16(af[mi], bfr[ni], acc[mi][ni], 0, 0, 0);
        __builtin_amdgcn_s_barrier();
    }

    if (which == 1 && by >= 12) {
        // ---- V^T via LDS bounce: coalesced 16B stores along token dim ----
        unsigned short* BT = &SM[0][0];
        const int c2b = nb - 1536;   // v-dim base
        #pragma unroll
        for (int half = 0; half < 2; ++half) {
            __syncthreads();
            if ((wr >> 6) == half) {
                #pragma unroll
                for (int mi = 0; mi < 4; ++mi)
                    #pragma unroll
                    for (int ni = 0; ni < 4; ++ni) {
                        const int col = wc + ni * 16 + l15;
                        const float bv = biascat[nb + col];
                        ushort4 pv;
                        pv.x = f2bf(acc[mi][ni][0] + bv);
                        pv.y = f2bf(acc[mi][ni][1] + bv);
                        pv.z = f2bf(acc[mi][ni][2] + bv);
                        pv.w = f2bf(acc[mi][ni][3] + bv);
                        *(ushort4*)(BT + col * 72 + mi * 16 + l4 * 4) = pv;
                    }
            }
            __syncthreads();
            const int c = tid >> 1;
            #pragma unroll
            for (int j = 0; j < 4; ++j) {
                const int seg = (tid & 1) * 4 + j;
                uint4 val = *(const uint4*)(BT + c * 72 + seg * 8);
                *(uint4*)(outB1 + (size_t)(c2b + c) * 4096 + mb + half * 64 + seg * 8) = val;
            }
        }
        return;
    }

    #pragma unroll
    for (int mi = 0; mi < 4; ++mi) {
        const int row0 = mb + wr + mi * 16 + l4 * 4;
        #pragma unroll
        for (int ni = 0; ni < 4; ++ni) {
            const int colg = nb + wc + ni * 16 + l15;
            const float bv = biascat[colg];
            float v[4];
            #pragma unroll
            for (int r = 0; r < 4; ++r) v[r] = acc[mi][ni][r] + bv;

            if (which == 0) {
                if (by < 4) {
                    #pragma unroll
                    for (int r = 0; r < 4; ++r) {
                        outF[(size_t)(row0 + r) * 512 + colg] = v[r];
                        outB0[(size_t)(row0 + r) * 512 + colg] = f2bf(v[r]);
                    }
                } else if (by < 8) {
                    const int c2 = colg - 512;
                    #pragma unroll
                    for (int r = 0; r < 4; ++r)
                        outB1[(size_t)(row0 + r) * 512 + c2] = f2bf(v[r]);
                } else {
                    const int cloc = colg - 1024, i2 = cloc & 31, h2 = cloc >> 5;
                    const float pbv = biascat[colg ^ 16];
                    const bool lo = (ni & 1) == 0;
                    #pragma unroll
                    for (int r = 0; r < 4; ++r) {
                        float vp = acc[mi][ni ^ 1][r] + pbv;
                        int t = (row0 + r) & 2047;
                        float cc_ = cs[t * 16 + (i2 & 15)], ss_ = sn[t * 16 + (i2 & 15)];
                        float o = lo ? (v[r] * cc_ - vp * ss_) : (v[r] * cc_ + vp * ss_);
                        outRope[(size_t)(row0 + r) * 512 + cloc] = o;
                        outB0k[(size_t)(row0 + r) * 2048 + h2 * 128 + 96 + i2] = f2bf(o);
                    }
                }
            } else if (which == 1) {
                const int ocol = (colg / 96) * 128 + colg % 96;
                #pragma unroll
                for (int r = 0; r < 4; ++r)
                    outB0[(size_t)(row0 + r) * 2048 + ocol] = f2bf(v[r]);
            } else if (which == 2) {
                if (by < 12) {
                    const int ocol = (colg / 96) * 128 + colg % 96;
                    #pragma unroll
                    for (int r = 0; r < 4; ++r)
                        outB0[(size_t)(row0 + r) * 2048 + ocol] = f2bf(v[r]);
                } else {
                    const int cloc = colg - 1536, i2 = cloc & 31, h2 = cloc >> 5;
                    const float pbv = biascat[colg ^ 16];
                    const bool lo = (ni & 1) == 0;
                    #pragma unroll
                    for (int r = 0; r < 4; ++r) {
                        float vp = acc[mi][ni ^ 1][r] + pbv;
                        int t = (row0 + r) & 2047;
                        float cc_ = cs[t * 16 + (i2 & 15)], ss_ = sn[t * 16 + (i2 & 15)];
                        float o = lo ? (v[r] * cc_ - vp * ss_) : (v[r] * cc_ + vp * ss_);
                        outB0[(size_t)(row0 + r) * 2048 + h2 * 128 + 96 + i2] = f2bf(o);
                    }
                }
            } else {
                #pragma unroll
                for (int r = 0; r < 4; ++r)
                    outF[(size_t)(row0 + r) * 2048 + colg] = v[r];
            }
        }
    }
}

// ---------- flash attention: swapped-QK^T 32x32 MFMA, in-register softmax ----------
// 1-D grid 512, XCD-swizzled: logical=(bid&7)*64+(bid>>3) -> 4 bh-groups (4MB K+V) per XCD L2.
// Counted-vmcnt raw-barrier pipeline: prefetch stays in flight across barriers.
__global__ __launch_bounds__(256, 2) void attn_kernel(const unsigned short* __restrict__ Q,
                                                      const unsigned short* __restrict__ Kb,
                                                      const unsigned short* __restrict__ Vtg,
                                                      unsigned short* __restrict__ O) {
    __shared__ __align__(16) unsigned short Ks[2][64 * 128];  // [key][d ^ ((key&7)<<3)]
    __shared__ __align__(16) unsigned short Vs[2][128 * 64];  // [d][k ^ ((d&7)<<3)]

    const int tid = threadIdx.x, w = tid >> 6, lane = tid & 63;
    const int l31 = lane & 31, hi = lane >> 5;
    const int bid = blockIdx.x;
    const int logical = (bid & 7) * 64 + (bid >> 3);
    const int bh = logical >> 4, b = bh >> 4, h = bh & 15;
    const int qt = (logical & 15) * 128 + w * 32;
    const int qrow = qt + l31;
    const float sl2e = 0.08838834764831845f * 1.4426950408889634f;  // scale*log2e

    bf16x8 qf[8];
    const unsigned short* qptr = Q + (size_t)(b * 2048 + qrow) * 2048 + h * 128 + hi * 8;
    #pragma unroll
    for (int s = 0; s < 8; ++s) qf[s] = *(const bf16x8*)(qptr + s * 16);

    f32x16 acc[4] = {};
    float m_run = -1e30f, l_run = 0.0f;

    const int kl15 = lane >> 4, kd0 = lane & 15;
    const int vr = lane >> 3, vk = lane & 7;

    // STAGE: 8 gload_lds per wave
    auto STAGE = [&](int buf, int kt) {
        #pragma unroll
        for (int i = 0; i < 4; ++i) {
            int c = w * 4 + i;
            int key = c * 4 + kl15;
            int d0 = (kd0 * 8) ^ ((key & 7) << 3);
            gload16(Kb + (size_t)(b * 2048 + kt + key) * 2048 + h * 128 + d0, &Ks[buf][c * 512]);
            int dv = c * 8 + vr;
            int k0 = (vk * 8) ^ ((dv & 7) << 3);
            gload16(Vtg + (size_t)(h * 128 + dv) * 4096 + b * 2048 + kt + k0, &Vs[buf][c * 512]);
        }
    };

    STAGE(0, 0);

    for (int t = 0; t < 32; ++t) {
        const int buf = t & 1;
        if (t < 31) {
            STAGE(buf ^ 1, (t + 1) * 64);
            asm volatile("s_waitcnt vmcnt(8)" ::: "memory");
        } else {
            asm volatile("s_waitcnt vmcnt(0)" ::: "memory");
        }
        __builtin_amdgcn_sched_barrier(0);
        __builtin_amdgcn_s_barrier();
        __builtin_amdgcn_sched_barrier(0);

        #pragma unroll
        for (int g = 0; g < 2; ++g) {
            const int key = g * 32 + l31;
            const unsigned short* kbase = &Ks[buf][key * 128];
            const int ksw = (key & 7) << 3;
            f32x16 sc = {};
            __builtin_amdgcn_s_setprio(1);
            #pragma unroll
            for (int s = 0; s < 8; ++s) {
                bf16x8 kf = *(const bf16x8*)(kbase + ((s * 16 + hi * 8) ^ ksw));
                sc = __builtin_amdgcn_mfma_f32_32x32x16_bf16(kf, qf[s], sc, 0, 0, 0);
            }
            __builtin_amdgcn_s_setprio(0);

            float pm = sc[0];
            #pragma unroll
            for (int i = 1; i < 16; ++i) pm = fmaxf(pm, sc[i]);
            pm = fmaxf(pm, __shfl_xor(pm, 32, 64));

            if (__any(pm > m_run + 90.51f)) {
                float mn = fmaxf(m_run, pm);
                float f = exp2a((m_run - mn) * sl2e);
                m_run = mn;
                l_run *= f;
                #pragma unroll
                for (int dg = 0; dg < 4; ++dg)
                    #pragma unroll
                    for (int i = 0; i < 16; ++i) acc[dg][i] *= f;
            }
            const float mexp2 = m_run * sl2e;

            float rs = 0.0f;
            #pragma unroll
            for (int s2 = 0; s2 < 2; ++s2) {
                float e[8];
                #pragma unroll
                for (int j = 0; j < 8; ++j) {
                    e[j] = exp2a(fmaf(sc[s2 * 8 + j], sl2e, -mexp2));
                    rs += e[j];
                }
                unsigned X0 = cvtpk_bf16(e[0], e[1]), X1 = cvtpk_bf16(e[2], e[3]);
                unsigned Y0 = cvtpk_bf16(e[4], e[5]), Y1 = cvtpk_bf16(e[6], e[7]);
                pl32swap(X0, Y0);
                pl32swap(X1, Y1);
                union { unsigned u[4]; bf16x8 v; } pf;
                pf.u[0] = X0; pf.u[1] = X1; pf.u[2] = Y0; pf.u[3] = Y1;

                const int kofs = g * 32 + s2 * 16 + hi * 8;
                __builtin_amdgcn_s_setprio(1);
                #pragma unroll
                for (int dg = 0; dg < 4; ++dg) {
                    const int d = dg * 32 + l31;
                    bf16x8 vf = *(const bf16x8*)(&Vs[buf][d * 64 + (kofs ^ ((d & 7) << 3))]);
                    acc[dg] = __builtin_amdgcn_mfma_f32_32x32x16_bf16(vf, pf.v, acc[dg], 0, 0, 0);
                }
                __builtin_amdgcn_s_setprio(0);
            }
            rs += __shfl_xor(rs, 32, 64);
            l_run += rs;
        }
        __builtin_amdgcn_s_barrier();
    }

    const float inv = 1.0f / l_run;
    unsigned short* obase = O + (size_t)(b * 2048 + qrow) * 2048 + h * 128;
    #pragma unroll
    for (int dg = 0; dg < 4; ++dg)
        #pragma unroll
        for (int k = 0; k < 4; ++k) {
            ushort4 pv;
            pv.x = f2bf(acc[dg][4 * k + 0] * inv);
            pv.y = f2bf(acc[dg][4 * k + 1] * inv);
            pv.z = f2bf(acc[dg][4 * k + 2] * inv);
            pv.w = f2bf(acc[dg][4 * k + 3] * inv);
            *(ushort4*)(obase + dg * 32 + k * 8 + hi * 4) = pv;
        }
}

extern "C" void kernel_launch(void* const* d_in, const int* in_sizes, int n_in,
                              void* d_out, int out_size, void* d_ws, size_t ws_size,
                              hipStream_t stream) {
    (void)in_sizes; (void)n_in; (void)out_size; (void)ws_size;

    const float* input  = (const float*)d_in[0];
    const float* Wdkv_w = (const float*)d_in[3];
    const float* Wdkv_b = (const float*)d_in[4];
    const float* Wdq_w  = (const float*)d_in[5];
    const float* Wdq_b  = (const float*)d_in[6];
    const float* Wuk_w  = (const float*)d_in[7];
    const float* Wuk_b  = (const float*)d_in[8];
    const float* Wuv_w  = (const float*)d_in[9];
    const float* Wuv_b  = (const float*)d_in[10];
    const float* Wuq_w  = (const float*)d_in[11];
    const float* Wuq_b  = (const float*)d_in[12];
    const float* Wqr_w  = (const float*)d_in[13];
    const float* Wqr_b  = (const float*)d_in[14];
    const float* Wkr_w  = (const float*)d_in[15];
    const float* Wkr_b  = (const float*)d_in[16];
    const float* Wo_w   = (const float*)d_in[17];
    const float* Wo_b   = (const float*)d_in[18];

    float* out_main = (float*)d_out;                       // [4096][2048]
    float* out_ckv  = out_main + (size_t)NROWS * DM;       // [4096][512]
    float* out_krot = out_ckv + (size_t)NROWS * LAT;       // [4096][512]

    char* p = (char*)d_ws;
    auto alloc = [&](size_t bytes) { char* r = p; p += (bytes + 255) & ~(size_t)255; return r; };
    unsigned short* x_bf  = (unsigned short*)alloc((size_t)NROWS * DM * 2);
    unsigned short* w1_t  = (unsigned short*)alloc((size_t)1536 * DM * 2);   // [dkv|dq|kr] x 2048
    unsigned short* w2_t  = (unsigned short*)alloc((size_t)3584 * LAT * 2);  // [uk|uv] x 512
    unsigned short* w3_t  = (unsigned short*)alloc((size_t)2048 * LAT * 2);  // [uq|qr] x 512
    unsigned short* w4_t  = (unsigned short*)alloc((size_t)DM * DM * 2);     // wo
    unsigned short* ckv_bf = (unsigned short*)alloc((size_t)NROWS * LAT * 2);
    unsigned short* cq_bf  = (unsigned short*)alloc((size_t)NROWS * LAT * 2);
    unsigned short* q_bf   = (unsigned short*)alloc((size_t)NROWS * DM * 2);
    unsigned short* k_bf   = (unsigned short*)alloc((size_t)NROWS * DM * 2);
    unsigned short* vt_g   = (unsigned short*)alloc((size_t)DM * NROWS * 2); // V^T [2048][4096]
    unsigned short* ao_bf  = (unsigned short*)alloc((size_t)NROWS * DM * 2);
    float* cos_t = (float*)alloc((size_t)2048 * 16 * 4);
    float* sin_t = (float*)alloc((size_t)2048 * 16 * 4);
    float* bc1 = (float*)alloc(1536 * 4);
    float* bc2 = (float*)alloc(3584 * 4);
    float* bc3 = (float*)alloc(2048 * 4);
    float* bc4 = (float*)alloc(2048 * 4);

    // ---- single prep dispatch ----
    PrepParams P;
    const float* tsrc[8] = {Wdkv_w, Wdq_w, Wkr_w, Wuk_w, Wuv_w, Wuq_w, Wqr_w, Wo_w};
    unsigned short* tdst[8] = {w1_t, w1_t + 512 * 2048, w1_t + 1024 * 2048,
                               w2_t, w2_t + 1536 * 512, w3_t, w3_t + 1536 * 512, w4_t};
    int tK[8] = {2048, 2048, 2048, 512, 512, 512, 512, 2048};
    int tN[8] = {512, 512, 512, 1536, 2048, 1536, 512, 2048};
    int tstart[8] = {0, 1024, 2048, 3072, 3840, 4864, 5632, 5888};
    const float* bsrc[8] = {Wdkv_b, Wdq_b, Wkr_b, Wuk_b, Wuv_b, Wuq_b, Wqr_b, Wo_b};
    float* bdst[8] = {bc1, bc1 + 512, bc1 + 1024, bc2, bc2 + 1536, bc3, bc3 + 1536, bc4};
    int blen[8] = {512, 512, 512, 1536, 2048, 1536, 512, 2048};
    for (int i = 0; i < 8; ++i) {
        P.tsrc[i] = tsrc[i]; P.tdst[i] = tdst[i]; P.tK[i] = tK[i]; P.tN[i] = tN[i];
        P.tstart[i] = tstart[i]; P.bsrc[i] = bsrc[i]; P.bdst[i] = bdst[i]; P.blen[i] = blen[i];
    }
    P.input = input; P.xbf = x_bf; P.cs = cos_t; P.sn = sin_t;
    prep_kernel<<<PREP_B_END, 256, 0, stream>>>(P);

    // G1: x @ [Wdkv|Wdq|Wkr] -> c_kv(f32+bf16), c_q(bf16), k_rot(rope: f32 out + k cols 96..127)
    gemm_fused_kernel<<<dim3(32, 12), 256, 0, stream>>>(x_bf, w1_t, bc1, 2048, 0,
                                                        out_ckv, ckv_bf, cq_bf, k_bf, out_krot, cos_t, sin_t);
    // G2: ckv @ [Wuk|Wuv] -> k_base(remap into k_bf), V^T (LDS-bounce coalesced)
    gemm_fused_kernel<<<dim3(32, 28), 256, 0, stream>>>(ckv_bf, w2_t, bc2, 512, 1,
                                                        nullptr, k_bf, vt_g, nullptr, nullptr, nullptr, nullptr);
    // G3: cq @ [Wuq|Wqr] -> q_base(remap) + q_rot(rope) into q_bf
    gemm_fused_kernel<<<dim3(32, 16), 256, 0, stream>>>(cq_bf, w3_t, bc3, 512, 2,
                                                        nullptr, q_bf, nullptr, nullptr, nullptr, cos_t, sin_t);

    // attention (1-D grid, XCD-swizzled)
    attn_kernel<<<512, 256, 0, stream>>>(q_bf, k_bf, vt_g, ao_bf);

    // G4: output projection
    gemm_fused_kernel<<<dim3(32, 16), 256, 0, stream>>>(ao_bf, w4_t, bc4, 2048, 3,
                                                        out_main, nullptr, nullptr, nullptr, nullptr, nullptr, nullptr);
}